// Round 1
// baseline (1242.025 us; speedup 1.0000x reference)
//
#include <hip/hip_runtime.h>
#include <math.h>

#define DIM      256
#define L_SEQ    1024
#define B_SZ     8
#define D_INNER  512
#define D_STATE  16
#define DT_RANK  16
#define N_TOK    (B_SZ * L_SEQ)   // 8192

// workspace float offsets
#define OFF_XN   0                       // 8192*256   = 2,097,152
#define OFF_XZ   2097152                 // 8192*1024  = 8,388,608  (reused as MLP hidden)
#define OFF_XC   10485760                // 8192*512   = 4,194,304  (reused in-place for gated y)
#define OFF_DBL  14680064                // 8192*48    =   393,216
#define OFF_DT   15073280                // 8192*512   = 4,194,304
#define OFF_XF2  19267584                // 8192*256   = 2,097,152
#define OFF_XN2  21364736                // 8192*256   = 2,097,152
// total: 23,461,888 floats = ~90 MB

// ---------------- LayerNorm over C=256, one block per token ----------------
__global__ __launch_bounds__(256) void ln_kernel(const float* __restrict__ in,
                                                 const float* __restrict__ g,
                                                 const float* __restrict__ b,
                                                 float* __restrict__ out,
                                                 int transposed_in) {
    int token = blockIdx.x;
    int c = threadIdx.x;
    float v;
    if (transposed_in) {
        int bb = token >> 10, l = token & 1023;
        v = in[((size_t)bb * DIM + c) * L_SEQ + l];
    } else {
        v = in[(size_t)token * DIM + c];
    }
    float s = v, s2 = v * v;
    #pragma unroll
    for (int o = 32; o; o >>= 1) {
        s  += __shfl_down(s, o);
        s2 += __shfl_down(s2, o);
    }
    __shared__ float red[8];
    int w = threadIdx.x >> 6;
    if ((threadIdx.x & 63) == 0) { red[w] = s; red[4 + w] = s2; }
    __syncthreads();
    if (threadIdx.x == 0) {
        float a = 0.f, aa = 0.f;
        for (int i = 0; i < 4; i++) { a += red[i]; aa += red[4 + i]; }
        red[0] = a; red[4] = aa;
    }
    __syncthreads();
    float mean = red[0] * (1.f / DIM);
    float var  = red[4] * (1.f / DIM) - mean * mean;
    float rstd = rsqrtf(var + 1e-5f);
    out[(size_t)token * DIM + c] = (v - mean) * rstd * g[c] + b[c];
}

// ---------------- fp32 GEMM: C[M,N] = A[M,K] @ W[N,K]^T, 64x64 tile ----------------
// EPI: 0 = plain store; 1 = + x residual (transposed read); 2 = bias+gelu; 3 = bias + res + transposed store
template <int EPI>
__global__ __launch_bounds__(256) void gemm_k(const float* __restrict__ A,
                                              const float* __restrict__ Bw,
                                              float* __restrict__ Cout,
                                              int M, int N, int K,
                                              const float* __restrict__ bias,
                                              const float* __restrict__ extra) {
    __shared__ float As[16][64];
    __shared__ float Bs[16][64];
    int tid = threadIdx.x;
    int tx = tid & 15, ty = tid >> 4;
    int m0 = blockIdx.y << 6, n0 = blockIdx.x << 6;
    int lr = tid >> 2, lc = (tid & 3) << 2;
    const float* Ap = A  + (size_t)(m0 + lr) * K + lc;
    const float* Bp = Bw + (size_t)(n0 + lr) * K + lc;
    float acc[4][4] = {};
    for (int k0 = 0; k0 < K; k0 += 16) {
        float4 a4 = *(const float4*)(Ap + k0);
        float4 b4 = *(const float4*)(Bp + k0);
        As[lc + 0][lr] = a4.x; As[lc + 1][lr] = a4.y; As[lc + 2][lr] = a4.z; As[lc + 3][lr] = a4.w;
        Bs[lc + 0][lr] = b4.x; Bs[lc + 1][lr] = b4.y; Bs[lc + 2][lr] = b4.z; Bs[lc + 3][lr] = b4.w;
        __syncthreads();
        #pragma unroll
        for (int kk = 0; kk < 16; kk++) {
            float4 av = *(const float4*)&As[kk][ty << 2];
            float4 bv = *(const float4*)&Bs[kk][tx << 2];
            float ar[4] = {av.x, av.y, av.z, av.w};
            float br[4] = {bv.x, bv.y, bv.z, bv.w};
            #pragma unroll
            for (int i = 0; i < 4; i++)
                #pragma unroll
                for (int j = 0; j < 4; j++)
                    acc[i][j] = fmaf(ar[i], br[j], acc[i][j]);
        }
        __syncthreads();
    }
    #pragma unroll
    for (int i = 0; i < 4; i++) {
        int m = m0 + (ty << 2) + i;
        int bb = m >> 10, l = m & 1023;
        #pragma unroll
        for (int j = 0; j < 4; j++) {
            int n = n0 + (tx << 2) + j;
            float v = acc[i][j];
            if (EPI == 0) {
                Cout[(size_t)m * N + n] = v;
            } else if (EPI == 1) {
                Cout[(size_t)m * N + n] = v + extra[((size_t)bb * DIM + n) * L_SEQ + l];
            } else if (EPI == 2) {
                v += bias[n];
                Cout[(size_t)m * N + n] = 0.5f * v * (1.f + erff(v * 0.70710678118f));
            } else {
                v += bias[n] + extra[(size_t)m * DIM + n];
                Cout[((size_t)bb * DIM + n) * L_SEQ + l] = v;
            }
        }
    }
}

// ---------------- depthwise causal conv (k=4) + silu ----------------
__global__ __launch_bounds__(256) void conv_kernel(const float* __restrict__ XZ,
                                                   const float* __restrict__ cw,
                                                   const float* __restrict__ cb,
                                                   float* __restrict__ XC) {
    int idx = blockIdx.x * 256 + threadIdx.x;   // (token, d), d fastest
    int d = idx & 511;
    int token = idx >> 9;
    int l = token & 1023, b = token >> 10;
    const float* base = XZ + (size_t)b * L_SEQ * 1024 + d;   // xi half: cols [0,512)
    float acc = cb[d];
    #pragma unroll
    for (int j = 0; j < 4; j++) {
        int ls = l - 3 + j;
        if (ls >= 0) acc = fmaf(base[(size_t)ls * 1024], cw[d * 4 + j], acc);
    }
    XC[(size_t)token * 512 + d] = acc / (1.f + __expf(-acc));   // silu
}

// ---------------- fused x_proj (48 outs) + dt_proj + softplus, one wave/token ----------------
__global__ __launch_bounds__(64) void xproj_kernel(const float* __restrict__ XC,
                                                   const float* __restrict__ x_proj_w,
                                                   const float* __restrict__ dt_proj_w,
                                                   const float* __restrict__ dt_proj_b,
                                                   float* __restrict__ DBL,
                                                   float* __restrict__ DT) {
    __shared__ float xrow[512];
    __shared__ float dbl_s[48];
    int token = blockIdx.x;
    int tid = threadIdx.x;
    const float4* src = (const float4*)(XC + (size_t)token * 512);
    ((float4*)xrow)[tid]      = src[tid];
    ((float4*)xrow)[tid + 64] = src[tid + 64];
    __syncthreads();
    if (tid < 48) {
        const float4* wr = (const float4*)(x_proj_w + (size_t)tid * 512);
        float acc = 0.f;
        #pragma unroll 4
        for (int k = 0; k < 128; k++) {
            float4 xv = ((const float4*)xrow)[k];
            float4 wv = wr[k];
            acc += xv.x * wv.x + xv.y * wv.y + xv.z * wv.z + xv.w * wv.w;
        }
        dbl_s[tid] = acc;
        if (tid >= 16) DBL[(size_t)token * 48 + tid] = acc;   // Bm [16,32), Cm [32,48)
    }
    __syncthreads();
    int d0 = tid * 8;
    for (int dd = 0; dd < 8; dd++) {
        int d = d0 + dd;
        const float4* wr = (const float4*)(dt_proj_w + d * 16);
        float acc = dt_proj_b[d];
        #pragma unroll
        for (int r4 = 0; r4 < 4; r4++) {
            float4 wv = wr[r4];
            acc += dbl_s[r4 * 4 + 0] * wv.x + dbl_s[r4 * 4 + 1] * wv.y +
                   dbl_s[r4 * 4 + 2] * wv.z + dbl_s[r4 * 4 + 3] * wv.w;
        }
        DT[(size_t)token * 512 + d] = (acc > 20.f) ? acc : log1pf(__expf(acc));
    }
}

// ---------------- selective scan: thread = (b, d, s); 16-lane shuffle reduce over s ----------------
__global__ __launch_bounds__(256) void scan_kernel(const float* __restrict__ U,
                                                   const float* __restrict__ DBL,
                                                   const float* __restrict__ DT,
                                                   const float* __restrict__ XZ,
                                                   const float* __restrict__ A_log,
                                                   const float* __restrict__ Dp,
                                                   float* __restrict__ YG) {
    int blk = blockIdx.x;                  // 256 blocks
    int b = blk >> 5, chunk = blk & 31;    // 32 chunks of 16 channels
    int tid = threadIdx.x;
    int s = tid & 15, dl = tid >> 4;
    int d = chunk * 16 + dl;
    float Ads = -__expf(A_log[d * D_STATE + s]);   // A = -exp(A_log)
    float Dv = Dp[d];
    const float* dtp = DT  + (size_t)b * L_SEQ * D_INNER + d;
    const float* up  = U   + (size_t)b * L_SEQ * D_INNER + d;
    const float* dbp = DBL + (size_t)b * L_SEQ * 48;
    const float* zp  = XZ  + (size_t)b * L_SEQ * 1024 + 512 + d;
    float* yp = YG + (size_t)b * L_SEQ * D_INNER + d;
    float h = 0.f;
    for (int t = 0; t < L_SEQ; t++) {
        float dtv = dtp[(size_t)t * D_INNER];
        float u   = up[(size_t)t * D_INNER];
        float bs  = dbp[t * 48 + 16 + s];
        float cs  = dbp[t * 48 + 32 + s];
        h = __expf(dtv * Ads) * h + dtv * bs * u;
        float yv = h * cs;
        yv += __shfl_xor(yv, 1);
        yv += __shfl_xor(yv, 2);
        yv += __shfl_xor(yv, 4);
        yv += __shfl_xor(yv, 8);
        if (s == 0) {
            float y = yv + u * Dv;
            float z = zp[(size_t)t * 1024];
            yp[(size_t)t * D_INNER] = y * (z / (1.f + __expf(-z)));   // * silu(z)
        }
    }
}

extern "C" void kernel_launch(void* const* d_in, const int* in_sizes, int n_in,
                              void* d_out, int out_size, void* d_ws, size_t ws_size,
                              hipStream_t stream) {
    (void)in_sizes; (void)n_in; (void)out_size; (void)ws_size;
    const float* x         = (const float*)d_in[0];
    const float* ln_g      = (const float*)d_in[1];
    const float* ln_b      = (const float*)d_in[2];
    const float* in_proj_w = (const float*)d_in[3];
    const float* conv_w    = (const float*)d_in[4];
    const float* conv_b    = (const float*)d_in[5];
    const float* x_proj_w  = (const float*)d_in[6];
    const float* dt_proj_w = (const float*)d_in[7];
    const float* dt_proj_b = (const float*)d_in[8];
    const float* A_log     = (const float*)d_in[9];
    const float* Dp        = (const float*)d_in[10];
    const float* out_proj_w= (const float*)d_in[11];
    const float* mlp_ln_g  = (const float*)d_in[12];
    const float* mlp_ln_b  = (const float*)d_in[13];
    const float* mlp_w1    = (const float*)d_in[14];
    const float* mlp_b1    = (const float*)d_in[15];
    const float* mlp_w2    = (const float*)d_in[16];
    const float* mlp_b2    = (const float*)d_in[17];

    float* ws  = (float*)d_ws;
    float* XN  = ws + OFF_XN;
    float* XZ  = ws + OFF_XZ;
    float* XC  = ws + OFF_XC;
    float* DBL = ws + OFF_DBL;
    float* DT  = ws + OFF_DT;
    float* XF2 = ws + OFF_XF2;
    float* XN2 = ws + OFF_XN2;
    float* out = (float*)d_out;

    // 1. LN1 on transposed x -> XN
    ln_kernel<<<N_TOK, 256, 0, stream>>>(x, ln_g, ln_b, XN, 1);
    // 2. in_proj: XZ[8192,1024] = XN @ in_proj_w^T
    gemm_k<0><<<dim3(1024 / 64, N_TOK / 64), 256, 0, stream>>>(XN, in_proj_w, XZ, N_TOK, 1024, 256, nullptr, nullptr);
    // 3. depthwise conv + silu -> XC
    conv_kernel<<<(N_TOK * D_INNER) / 256, 256, 0, stream>>>(XZ, conv_w, conv_b, XC);
    // 4. x_proj + dt_proj + softplus -> DBL (B,C), DT
    xproj_kernel<<<N_TOK, 64, 0, stream>>>(XC, x_proj_w, dt_proj_w, dt_proj_b, DBL, DT);
    // 5. selective scan + *silu(z), in-place into XC
    scan_kernel<<<256, 256, 0, stream>>>(XC, DBL, DT, XZ, A_log, Dp, XC);
    // 6. out_proj + residual(x transposed) -> XF2
    gemm_k<1><<<dim3(256 / 64, N_TOK / 64), 256, 0, stream>>>(XC, out_proj_w, XF2, N_TOK, 256, 512, nullptr, x);
    // 7. LN2 -> XN2
    ln_kernel<<<N_TOK, 256, 0, stream>>>(XF2, mlp_ln_g, mlp_ln_b, XN2, 0);
    // 8. MLP fc1 + gelu -> XZ (reuse)
    gemm_k<2><<<dim3(1024 / 64, N_TOK / 64), 256, 0, stream>>>(XN2, mlp_w1, XZ, N_TOK, 1024, 256, mlp_b1, nullptr);
    // 9. MLP fc2 + b2 + residual, transposed store -> d_out
    gemm_k<3><<<dim3(256 / 64, N_TOK / 64), 256, 0, stream>>>(XZ, mlp_w2, out, N_TOK, 256, 1024, mlp_b2, XF2);
}

// Round 3
// 736.693 us; speedup vs baseline: 1.6859x; 1.6859x over previous
//
#include <hip/hip_runtime.h>
#include <math.h>

#define DIM      256
#define L_SEQ    1024
#define B_SZ     8
#define D_INNER  512
#define D_STATE  16
#define DT_RANK  16
#define N_TOK    (B_SZ * L_SEQ)   // 8192

// workspace float offsets
#define OFF_XN   0                       // 8192*256   = 2,097,152
#define OFF_XZ   2097152                 // 8192*1024  = 8,388,608  (reused as MLP hidden)
#define OFF_XC   10485760                // 8192*512   = 4,194,304  (reused in-place for gated y)
#define OFF_DBL  14680064                // 8192*48    =   393,216
#define OFF_DT   15073280                // 8192*512   = 4,194,304
#define OFF_XF2  19267584                // 8192*256   = 2,097,152
#define OFF_XN2  21364736                // 8192*256   = 2,097,152

// ---------------- LayerNorm over C=256, one block per token ----------------
__global__ __launch_bounds__(256) void ln_kernel(const float* __restrict__ in,
                                                 const float* __restrict__ g,
                                                 const float* __restrict__ b,
                                                 float* __restrict__ out,
                                                 int transposed_in) {
    int token = blockIdx.x;
    int c = threadIdx.x;
    float v;
    if (transposed_in) {
        int bb = token >> 10, l = token & 1023;
        v = in[((size_t)bb * DIM + c) * L_SEQ + l];
    } else {
        v = in[(size_t)token * DIM + c];
    }
    float s = v, s2 = v * v;
    #pragma unroll
    for (int o = 32; o; o >>= 1) {
        s  += __shfl_down(s, o);
        s2 += __shfl_down(s2, o);
    }
    __shared__ float red[8];
    int w = threadIdx.x >> 6;
    if ((threadIdx.x & 63) == 0) { red[w] = s; red[4 + w] = s2; }
    __syncthreads();
    if (threadIdx.x == 0) {
        float a = 0.f, aa = 0.f;
        for (int i = 0; i < 4; i++) { a += red[i]; aa += red[4 + i]; }
        red[0] = a; red[4] = aa;
    }
    __syncthreads();
    float mean = red[0] * (1.f / DIM);
    float var  = red[4] * (1.f / DIM) - mean * mean;
    float rstd = rsqrtf(var + 1e-5f);
    out[(size_t)token * DIM + c] = (v - mean) * rstd * g[c] + b[c];
}

// ---------------- fp32 GEMM: C[M,N] = A[M,K] @ W[N,K]^T, 64x64 tile ----------------
// EPI: 0 = plain store; 1 = + x residual (transposed read); 2 = bias+gelu; 3 = bias + res + transposed store
template <int EPI>
__global__ __launch_bounds__(256) void gemm_k(const float* __restrict__ A,
                                              const float* __restrict__ Bw,
                                              float* __restrict__ Cout,
                                              int M, int N, int K,
                                              const float* __restrict__ bias,
                                              const float* __restrict__ extra) {
    __shared__ float As[16][64];
    __shared__ float Bs[16][64];
    int tid = threadIdx.x;
    int tx = tid & 15, ty = tid >> 4;
    int m0 = blockIdx.y << 6, n0 = blockIdx.x << 6;
    int lr = tid >> 2, lc = (tid & 3) << 2;
    const float* Ap = A  + (size_t)(m0 + lr) * K + lc;
    const float* Bp = Bw + (size_t)(n0 + lr) * K + lc;
    float acc[4][4] = {};
    for (int k0 = 0; k0 < K; k0 += 16) {
        float4 a4 = *(const float4*)(Ap + k0);
        float4 b4 = *(const float4*)(Bp + k0);
        As[lc + 0][lr] = a4.x; As[lc + 1][lr] = a4.y; As[lc + 2][lr] = a4.z; As[lc + 3][lr] = a4.w;
        Bs[lc + 0][lr] = b4.x; Bs[lc + 1][lr] = b4.y; Bs[lc + 2][lr] = b4.z; Bs[lc + 3][lr] = b4.w;
        __syncthreads();
        #pragma unroll
        for (int kk = 0; kk < 16; kk++) {
            float4 av = *(const float4*)&As[kk][ty << 2];
            float4 bv = *(const float4*)&Bs[kk][tx << 2];
            float ar[4] = {av.x, av.y, av.z, av.w};
            float br[4] = {bv.x, bv.y, bv.z, bv.w};
            #pragma unroll
            for (int i = 0; i < 4; i++)
                #pragma unroll
                for (int j = 0; j < 4; j++)
                    acc[i][j] = fmaf(ar[i], br[j], acc[i][j]);
        }
        __syncthreads();
    }
    #pragma unroll
    for (int i = 0; i < 4; i++) {
        int m = m0 + (ty << 2) + i;
        int bb = m >> 10, l = m & 1023;
        #pragma unroll
        for (int j = 0; j < 4; j++) {
            int n = n0 + (tx << 2) + j;
            float v = acc[i][j];
            if (EPI == 0) {
                Cout[(size_t)m * N + n] = v;
            } else if (EPI == 1) {
                Cout[(size_t)m * N + n] = v + extra[((size_t)bb * DIM + n) * L_SEQ + l];
            } else if (EPI == 2) {
                v += bias[n];
                Cout[(size_t)m * N + n] = 0.5f * v * (1.f + erff(v * 0.70710678118f));
            } else {
                v += bias[n] + extra[(size_t)m * DIM + n];
                Cout[((size_t)bb * DIM + n) * L_SEQ + l] = v;
            }
        }
    }
}

// ---------------- depthwise causal conv (k=4) + silu ----------------
__global__ __launch_bounds__(256) void conv_kernel(const float* __restrict__ XZ,
                                                   const float* __restrict__ cw,
                                                   const float* __restrict__ cb,
                                                   float* __restrict__ XC) {
    int idx = blockIdx.x * 256 + threadIdx.x;   // (token, d), d fastest
    int d = idx & 511;
    int token = idx >> 9;
    int l = token & 1023, b = token >> 10;
    const float* base = XZ + (size_t)b * L_SEQ * 1024 + d;   // xi half: cols [0,512)
    float acc = cb[d];
    #pragma unroll
    for (int j = 0; j < 4; j++) {
        int ls = l - 3 + j;
        if (ls >= 0) acc = fmaf(base[(size_t)ls * 1024], cw[d * 4 + j], acc);
    }
    XC[(size_t)token * 512 + d] = acc / (1.f + __expf(-acc));   // silu
}

// ---------------- fused x_proj (48 outs) + dt_proj + softplus, one wave/token ----------------
__global__ __launch_bounds__(64) void xproj_kernel(const float* __restrict__ XC,
                                                   const float* __restrict__ x_proj_w,
                                                   const float* __restrict__ dt_proj_w,
                                                   const float* __restrict__ dt_proj_b,
                                                   float* __restrict__ DBL,
                                                   float* __restrict__ DT) {
    __shared__ float xrow[512];
    __shared__ float dbl_s[48];
    int token = blockIdx.x;
    int tid = threadIdx.x;
    const float4* src = (const float4*)(XC + (size_t)token * 512);
    ((float4*)xrow)[tid]      = src[tid];
    ((float4*)xrow)[tid + 64] = src[tid + 64];
    __syncthreads();
    if (tid < 48) {
        const float4* wr = (const float4*)(x_proj_w + (size_t)tid * 512);
        float acc = 0.f;
        #pragma unroll 4
        for (int k = 0; k < 128; k++) {
            float4 xv = ((const float4*)xrow)[k];
            float4 wv = wr[k];
            acc += xv.x * wv.x + xv.y * wv.y + xv.z * wv.z + xv.w * wv.w;
        }
        dbl_s[tid] = acc;
        if (tid >= 16) DBL[(size_t)token * 48 + tid] = acc;   // Bm [16,32), Cm [32,48)
    }
    __syncthreads();
    int d0 = tid * 8;
    for (int dd = 0; dd < 8; dd++) {
        int d = d0 + dd;
        const float4* wr = (const float4*)(dt_proj_w + d * 16);
        float acc = dt_proj_b[d];
        #pragma unroll
        for (int r4 = 0; r4 < 4; r4++) {
            float4 wv = wr[r4];
            acc += dbl_s[r4 * 4 + 0] * wv.x + dbl_s[r4 * 4 + 1] * wv.y +
                   dbl_s[r4 * 4 + 2] * wv.z + dbl_s[r4 * 4 + 3] * wv.w;
        }
        DT[(size_t)token * 512 + d] = (acc > 20.f) ? acc : log1pf(__expf(acc));
    }
}

// ---------------- selective scan v2: LDS-staged, double-buffered, exp hoisted ----------------
// block = (b, chunk of 16 channels). 256 blocks x 256 threads. thread = (dl, s).
// L processed in 16 chunks of T_CH=64 steps. Staging via global_load_lds (16B),
// LDS layouts linear in tid order (wave-uniform base + lane*16 constraint).
#define T_CH 64

__device__ __forceinline__ void gload16(const float* g, float* l) {
    __builtin_amdgcn_global_load_lds(
        (const __attribute__((address_space(1))) unsigned int*)g,
        (__attribute__((address_space(3))) unsigned int*)l,
        16, 0, 0);
}

__global__ __launch_bounds__(256) void scan_kernel(const float* __restrict__ U,
                                                   const float* __restrict__ DBL,
                                                   const float* __restrict__ DT,
                                                   const float* __restrict__ XZ,
                                                   const float* __restrict__ A_log,
                                                   const float* __restrict__ Dp,
                                                   float* __restrict__ YG) {
    __shared__ float s_dt[2][T_CH][16];
    __shared__ float s_u [2][T_CH][16];
    __shared__ float s_BC[2][T_CH][32];   // B in cols [0,16), C in [16,32)
    __shared__ float s_z [2][T_CH][16];
    __shared__ float s_y [2][T_CH][16];

    int blk = blockIdx.x;
    int b = blk >> 5, ch = blk & 31;       // 16-channel group
    int tid = threadIdx.x;
    int s = tid & 15, dl = tid >> 4;
    int d = ch * 16 + dl;
    int w = tid >> 6;                      // wave id

    float Ads = -__expf(A_log[d * D_STATE + s]);
    float Dv = Dp[d];

    const float* DTb = DT  + (size_t)b * L_SEQ * D_INNER + ch * 16;
    const float* Ub  = U   + (size_t)b * L_SEQ * D_INNER + ch * 16;
    const float* DBb = DBL + (size_t)b * L_SEQ * 48 + 16;
    const float* Zb  = XZ  + (size_t)b * L_SEQ * 1024 + 512 + ch * 16;
    float* Yb        = YG  + (size_t)b * L_SEQ * D_INNER + ch * 16;

    // staging lane mapping: 16-float rows -> r = tid>>2, q = tid&3 (float4)
    int r16 = tid >> 2, q16 = (tid & 3) << 2;
    // BC: 32-float rows -> idx = k*256+tid; r = idx>>3, q = idx&7
    int r32 = tid >> 3, q32 = (tid & 7) << 2;

    #define STAGE(c, bf) { \
        int t0_ = (c) * T_CH; \
        gload16(DTb + (size_t)(t0_ + r16) * 512 + q16, &s_dt[bf][0][0] + (w << 8)); \
        gload16(Ub  + (size_t)(t0_ + r16) * 512 + q16, &s_u [bf][0][0] + (w << 8)); \
        gload16(Zb  + (size_t)(t0_ + r16) * 1024 + q16, &s_z[bf][0][0] + (w << 8)); \
        gload16(DBb + (size_t)(t0_ + r32) * 48 + q32, &s_BC[bf][0][0] + (w << 8)); \
        gload16(DBb + (size_t)(t0_ + 32 + r32) * 48 + q32, &s_BC[bf][0][0] + 1024 + (w << 8)); \
    }

    float h = 0.f;
    int bf = 0;
    STAGE(0, 0);
    __syncthreads();   // drains vmcnt -> chunk 0 staged

    for (int c = 0; c < L_SEQ / T_CH; c++) {
        if (c + 1 < L_SEQ / T_CH) STAGE(c + 1, bf ^ 1);
        int yb = c & 1;
        // compute chunk c from buf bf
        #pragma unroll 1
        for (int tb = 0; tb < 4; tb++) {
            float da[16], db[16], cc[16], uu[16];
            #pragma unroll
            for (int j = 0; j < 16; j++) {
                int t = (tb << 4) + j;
                float dtv = s_dt[bf][t][dl];
                float uv  = s_u [bf][t][dl];
                float bs  = s_BC[bf][t][s];
                float cs  = s_BC[bf][t][16 + s];
                da[j] = __expf(dtv * Ads);
                db[j] = dtv * bs * uv;
                cc[j] = cs;
                uu[j] = uv;
            }
            #pragma unroll
            for (int j = 0; j < 16; j++) {
                h = fmaf(da[j], h, db[j]);
                float yv = h * cc[j];
                yv += __shfl_xor(yv, 1);
                yv += __shfl_xor(yv, 2);
                yv += __shfl_xor(yv, 4);
                yv += __shfl_xor(yv, 8);
                if (s == 0) {
                    int t = (tb << 4) + j;
                    float zv = s_z[bf][t][dl];
                    float y = yv + uu[j] * Dv;
                    s_y[yb][t][dl] = y * (zv / (1.f + __expf(-zv)));
                }
            }
        }
        __syncthreads();   // s_y visible; prefetch (issued pre-compute) landed
        // bulk store y chunk: coalesced float4
        {
            int t0_ = c * T_CH;
            float4 v = *(const float4*)(&s_y[yb][0][0] + (tid << 2));
            *(float4*)(Yb + (size_t)(t0_ + r16) * 512 + q16) = v;
        }
        bf ^= 1;
    }
    #undef STAGE
}

extern "C" void kernel_launch(void* const* d_in, const int* in_sizes, int n_in,
                              void* d_out, int out_size, void* d_ws, size_t ws_size,
                              hipStream_t stream) {
    (void)in_sizes; (void)n_in; (void)out_size; (void)ws_size;
    const float* x         = (const float*)d_in[0];
    const float* ln_g      = (const float*)d_in[1];
    const float* ln_b      = (const float*)d_in[2];
    const float* in_proj_w = (const float*)d_in[3];
    const float* conv_w    = (const float*)d_in[4];
    const float* conv_b    = (const float*)d_in[5];
    const float* x_proj_w  = (const float*)d_in[6];
    const float* dt_proj_w = (const float*)d_in[7];
    const float* dt_proj_b = (const float*)d_in[8];
    const float* A_log     = (const float*)d_in[9];
    const float* Dp        = (const float*)d_in[10];
    const float* out_proj_w= (const float*)d_in[11];
    const float* mlp_ln_g  = (const float*)d_in[12];
    const float* mlp_ln_b  = (const float*)d_in[13];
    const float* mlp_w1    = (const float*)d_in[14];
    const float* mlp_b1    = (const float*)d_in[15];
    const float* mlp_w2    = (const float*)d_in[16];
    const float* mlp_b2    = (const float*)d_in[17];

    float* ws  = (float*)d_ws;
    float* XN  = ws + OFF_XN;
    float* XZ  = ws + OFF_XZ;
    float* XC  = ws + OFF_XC;
    float* DBL = ws + OFF_DBL;
    float* DT  = ws + OFF_DT;
    float* XF2 = ws + OFF_XF2;
    float* XN2 = ws + OFF_XN2;
    float* out = (float*)d_out;

    // 1. LN1 on transposed x -> XN
    ln_kernel<<<N_TOK, 256, 0, stream>>>(x, ln_g, ln_b, XN, 1);
    // 2. in_proj: XZ[8192,1024] = XN @ in_proj_w^T
    gemm_k<0><<<dim3(1024 / 64, N_TOK / 64), 256, 0, stream>>>(XN, in_proj_w, XZ, N_TOK, 1024, 256, nullptr, nullptr);
    // 3. depthwise conv + silu -> XC
    conv_kernel<<<(N_TOK * D_INNER) / 256, 256, 0, stream>>>(XZ, conv_w, conv_b, XC);
    // 4. x_proj + dt_proj + softplus -> DBL (B,C), DT
    xproj_kernel<<<N_TOK, 64, 0, stream>>>(XC, x_proj_w, dt_proj_w, dt_proj_b, DBL, DT);
    // 5. selective scan + *silu(z), in-place into XC
    scan_kernel<<<256, 256, 0, stream>>>(XC, DBL, DT, XZ, A_log, Dp, XC);
    // 6. out_proj + residual(x transposed) -> XF2
    gemm_k<1><<<dim3(256 / 64, N_TOK / 64), 256, 0, stream>>>(XC, out_proj_w, XF2, N_TOK, 256, 512, nullptr, x);
    // 7. LN2 -> XN2
    ln_kernel<<<N_TOK, 256, 0, stream>>>(XF2, mlp_ln_g, mlp_ln_b, XN2, 0);
    // 8. MLP fc1 + gelu -> XZ (reuse)
    gemm_k<2><<<dim3(1024 / 64, N_TOK / 64), 256, 0, stream>>>(XN2, mlp_w1, XZ, N_TOK, 1024, 256, mlp_b1, nullptr);
    // 9. MLP fc2 + b2 + residual, transposed store -> d_out
    gemm_k<3><<<dim3(256 / 64, N_TOK / 64), 256, 0, stream>>>(XZ, mlp_w2, out, N_TOK, 256, 1024, mlp_b2, XF2);
}

// Round 4
// 446.167 us; speedup vs baseline: 2.7838x; 1.6512x over previous
//
#include <hip/hip_runtime.h>
#include <math.h>

#define DIM      256
#define L_SEQ    1024
#define B_SZ     8
#define D_INNER  512
#define D_STATE  16
#define DT_RANK  16
#define N_TOK    (B_SZ * L_SEQ)   // 8192

typedef unsigned short u16;
typedef __attribute__((ext_vector_type(4))) float f32x4;
typedef __attribute__((ext_vector_type(8))) short short8;
struct __align__(8) us4 { u16 x, y, z, w; };

// workspace float offsets (91.5 MB total; H aliases XZ, XN2 aliases XN)
#define OFF_XNB  0                     // bf16 8192x256   -> 1,048,576 floats (also XN2)
#define OFF_XZ   1048576               // fp32 8192x1024  -> 8,388,608 (also H bf16 8192x1024 = 4,194,304)
#define OFF_XC   9437184               // fp32 8192x512   -> 4,194,304
#define OFF_DBL  13631488              // fp32 8192x48    ->   393,216
#define OFF_DT   14024704              // fp32 8192x512   -> 4,194,304
#define OFF_XF2  18219008              // fp32 8192x256   -> 2,097,152
#define OFF_YB   20316160              // bf16 8192x512   -> 2,097,152 floats
#define OFF_WB   22413312              // bf16 weights    ->   458,752 floats
// WB sub-offsets in u16 elements
#define WB_IN    0         // 262144
#define WB_OUT   262144    // 131072
#define WB_W1    393216    // 262144
#define WB_W2    655360    // 262144

__device__ __forceinline__ u16 f2b(float f) {
    unsigned int u = __float_as_uint(f);
    return (u16)((u + 0x7fffu + ((u >> 16) & 1u)) >> 16);   // RNE
}

// ---------------- weight fp32->bf16 convert (4 segments, one launch) ----------------
__global__ __launch_bounds__(256) void cvt4_kernel(const float* __restrict__ a,
                                                   const float* __restrict__ b,
                                                   const float* __restrict__ c,
                                                   const float* __restrict__ d,
                                                   u16* __restrict__ out) {
    int i = blockIdx.x * 256 + threadIdx.x;   // total 917504
    const float* src; int off;
    if (i < 262144)      { src = a; off = i; }
    else if (i < 393216) { src = b; off = i - 262144; }
    else if (i < 655360) { src = c; off = i - 393216; }
    else                 { src = d; off = i - 655360; }
    out[i] = f2b(src[off]);
}

// ---------------- LayerNorm over C=256, one block per token; bf16 out ----------------
__global__ __launch_bounds__(256) void ln_kernel(const float* __restrict__ in,
                                                 const float* __restrict__ g,
                                                 const float* __restrict__ b,
                                                 u16* __restrict__ out,
                                                 int transposed_in) {
    int token = blockIdx.x;
    int c = threadIdx.x;
    float v;
    if (transposed_in) {
        int bb = token >> 10, l = token & 1023;
        v = in[((size_t)bb * DIM + c) * L_SEQ + l];
    } else {
        v = in[(size_t)token * DIM + c];
    }
    float s = v, s2 = v * v;
    #pragma unroll
    for (int o = 32; o; o >>= 1) {
        s  += __shfl_down(s, o);
        s2 += __shfl_down(s2, o);
    }
    __shared__ float red[8];
    int w = threadIdx.x >> 6;
    if ((threadIdx.x & 63) == 0) { red[w] = s; red[4 + w] = s2; }
    __syncthreads();
    if (threadIdx.x == 0) {
        float a = 0.f, aa = 0.f;
        for (int i = 0; i < 4; i++) { a += red[i]; aa += red[4 + i]; }
        red[0] = a; red[4] = aa;
    }
    __syncthreads();
    float mean = red[0] * (1.f / DIM);
    float var  = red[4] * (1.f / DIM) - mean * mean;
    float rstd = rsqrtf(var + 1e-5f);
    out[(size_t)token * DIM + c] = f2b((v - mean) * rstd * g[c] + b[c]);
}

// ---------------- global->LDS async helper (16B) ----------------
__device__ __forceinline__ void gload16(const void* g, void* l) {
    __builtin_amdgcn_global_load_lds(
        (const __attribute__((address_space(1))) unsigned int*)g,
        (__attribute__((address_space(3))) unsigned int*)l,
        16, 0, 0);
}

// ---------------- bf16 MFMA GEMM: C[M,N] = A[M,K] @ W[N,K]^T ----------------
// 128x128 tile, BK=32, 4 waves (2x2), each wave 64x64 = 4x4 frags of 16x16x32.
// EPI: 0 = fp32 store; 1 = fp32 + residual (transposed read); 2 = bias+gelu, bf16 store;
//      3 = bias + residual + transposed fp32 store
template <int EPI>
__global__ __launch_bounds__(256) void gemm_mfma(const u16* __restrict__ A,
                                                 const u16* __restrict__ W,
                                                 void* __restrict__ Cout,
                                                 int M, int N, int K,
                                                 const float* __restrict__ bias,
                                                 const float* __restrict__ extra) {
    __shared__ u16 Als[4096];   // [128][32] bf16, row-major
    __shared__ u16 Bls[4096];
    int tid = threadIdx.x;
    int w = tid >> 6, l = tid & 63;
    int m0 = blockIdx.y << 7, n0 = blockIdx.x << 7;

    // staging: call i in {0,1}, thread writes 8 bf16 at linear elem tid*8 (+ i*2048)
    int srow = tid >> 2;              // 0..63
    int scol = (tid & 3) << 3;        // 0,8,16,24
    const u16* Ag  = A + (size_t)(m0 + srow) * K + scol;
    const u16* Ag2 = A + (size_t)(m0 + 64 + srow) * K + scol;
    const u16* Wg  = W + (size_t)(n0 + srow) * K + scol;
    const u16* Wg2 = W + (size_t)(n0 + 64 + srow) * K + scol;
    u16* Ab0 = Als + (w << 9);         // wave-uniform LDS bases (HW adds lane*16B)
    u16* Ab1 = Als + 2048 + (w << 9);
    u16* Bb0 = Bls + (w << 9);
    u16* Bb1 = Bls + 2048 + (w << 9);

    int wr = (w >> 1) << 6, wc = (w & 1) << 6;   // wave output origin in tile
    int fr = l & 15, fk = (l >> 4) << 3;         // frag row/col = lane&15, k-slice = (lane>>4)*8

    f32x4 acc[4][4] = {};
    for (int k0 = 0; k0 < K; k0 += 32) {
        gload16(Ag + k0, Ab0);
        gload16(Ag2 + k0, Ab1);
        gload16(Wg + k0, Bb0);
        gload16(Wg2 + k0, Bb1);
        __syncthreads();
        short8 af[4], bfr[4];
        #pragma unroll
        for (int i = 0; i < 4; i++)
            af[i] = *(const short8*)&Als[(wr + i * 16 + fr) * 32 + fk];
        #pragma unroll
        for (int j = 0; j < 4; j++)
            bfr[j] = *(const short8*)&Bls[(wc + j * 16 + fr) * 32 + fk];
        #pragma unroll
        for (int i = 0; i < 4; i++)
            #pragma unroll
            for (int j = 0; j < 4; j++)
                acc[i][j] = __builtin_amdgcn_mfma_f32_16x16x32_bf16(af[i], bfr[j], acc[i][j], 0, 0, 0);
        __syncthreads();
    }

    // epilogue: C/D layout col = lane&15, row = (lane>>4)*4 + reg  [m89-verified]
    int cr = (l >> 4) << 2;
    int ccol = l & 15;
    #pragma unroll
    for (int i = 0; i < 4; i++) {
        #pragma unroll
        for (int j = 0; j < 4; j++) {
            int n = n0 + wc + j * 16 + ccol;
            #pragma unroll
            for (int r = 0; r < 4; r++) {
                int m = m0 + wr + i * 16 + cr + r;
                int bb = m >> 10, ll = m & 1023;
                float v = acc[i][j][r];
                if (EPI == 0) {
                    ((float*)Cout)[(size_t)m * N + n] = v;
                } else if (EPI == 1) {
                    ((float*)Cout)[(size_t)m * N + n] = v + extra[((size_t)bb * DIM + n) * L_SEQ + ll];
                } else if (EPI == 2) {
                    v += bias[n];
                    ((u16*)Cout)[(size_t)m * N + n] = f2b(0.5f * v * (1.f + erff(v * 0.70710678118f)));
                } else {
                    v += bias[n] + extra[(size_t)m * DIM + n];
                    ((float*)Cout)[((size_t)bb * DIM + n) * L_SEQ + ll] = v;
                }
            }
        }
    }
}

// ---------------- depthwise causal conv (k=4) + silu ----------------
__global__ __launch_bounds__(256) void conv_kernel(const float* __restrict__ XZ,
                                                   const float* __restrict__ cw,
                                                   const float* __restrict__ cb,
                                                   float* __restrict__ XC) {
    int idx = blockIdx.x * 256 + threadIdx.x;
    int d = idx & 511;
    int token = idx >> 9;
    int l = token & 1023, b = token >> 10;
    const float* base = XZ + (size_t)b * L_SEQ * 1024 + d;
    float acc = cb[d];
    #pragma unroll
    for (int j = 0; j < 4; j++) {
        int ls = l - 3 + j;
        if (ls >= 0) acc = fmaf(base[(size_t)ls * 1024], cw[d * 4 + j], acc);
    }
    XC[(size_t)token * 512 + d] = acc / (1.f + __expf(-acc));
}

// ---------------- fused x_proj (48 outs) + dt_proj + softplus, one wave/token ----------------
__global__ __launch_bounds__(64) void xproj_kernel(const float* __restrict__ XC,
                                                   const float* __restrict__ x_proj_w,
                                                   const float* __restrict__ dt_proj_w,
                                                   const float* __restrict__ dt_proj_b,
                                                   float* __restrict__ DBL,
                                                   float* __restrict__ DT) {
    __shared__ float xrow[512];
    __shared__ float dbl_s[48];
    int token = blockIdx.x;
    int tid = threadIdx.x;
    const float4* src = (const float4*)(XC + (size_t)token * 512);
    ((float4*)xrow)[tid]      = src[tid];
    ((float4*)xrow)[tid + 64] = src[tid + 64];
    __syncthreads();
    if (tid < 48) {
        const float4* wr = (const float4*)(x_proj_w + (size_t)tid * 512);
        float acc = 0.f;
        #pragma unroll 4
        for (int k = 0; k < 128; k++) {
            float4 xv = ((const float4*)xrow)[k];
            float4 wv = wr[k];
            acc += xv.x * wv.x + xv.y * wv.y + xv.z * wv.z + xv.w * wv.w;
        }
        dbl_s[tid] = acc;
        if (tid >= 16) DBL[(size_t)token * 48 + tid] = acc;
    }
    __syncthreads();
    int d0 = tid * 8;
    for (int dd = 0; dd < 8; dd++) {
        int d = d0 + dd;
        const float4* wr = (const float4*)(dt_proj_w + d * 16);
        float acc = dt_proj_b[d];
        #pragma unroll
        for (int r4 = 0; r4 < 4; r4++) {
            float4 wv = wr[r4];
            acc += dbl_s[r4 * 4 + 0] * wv.x + dbl_s[r4 * 4 + 1] * wv.y +
                   dbl_s[r4 * 4 + 2] * wv.z + dbl_s[r4 * 4 + 3] * wv.w;
        }
        DT[(size_t)token * 512 + d] = (acc > 20.f) ? acc : log1pf(__expf(acc));
    }
}

// ---------------- selective scan v3: batched shuffle reduce, bf16 y out ----------------
#define T_CH 64
__global__ __launch_bounds__(256) void scan_kernel(const float* __restrict__ U,
                                                   const float* __restrict__ DBL,
                                                   const float* __restrict__ DT,
                                                   const float* __restrict__ XZ,
                                                   const float* __restrict__ A_log,
                                                   const float* __restrict__ Dp,
                                                   u16* __restrict__ YB) {
    __shared__ float s_dt[2][T_CH][16];
    __shared__ float s_u [2][T_CH][16];
    __shared__ float s_BC[2][T_CH][32];
    __shared__ float s_z [2][T_CH][16];
    __shared__ float s_y [2][T_CH][16];

    int blk = blockIdx.x;
    int b = blk >> 5, ch = blk & 31;
    int tid = threadIdx.x;
    int s = tid & 15, dl = tid >> 4;
    int d = ch * 16 + dl;
    int w = tid >> 6;

    float Ads = -__expf(A_log[d * D_STATE + s]);
    float Dv = Dp[d];

    const float* DTb = DT  + (size_t)b * L_SEQ * D_INNER + ch * 16;
    const float* Ub  = U   + (size_t)b * L_SEQ * D_INNER + ch * 16;
    const float* DBb = DBL + (size_t)b * L_SEQ * 48 + 16;
    const float* Zb  = XZ  + (size_t)b * L_SEQ * 1024 + 512 + ch * 16;
    u16* Yb          = YB  + (size_t)b * L_SEQ * D_INNER + ch * 16;

    int r16 = tid >> 2, q16 = (tid & 3) << 2;
    int r32 = tid >> 3, q32 = (tid & 7) << 2;

    #define STAGE(c, bf) { \
        int t0_ = (c) * T_CH; \
        gload16(DTb + (size_t)(t0_ + r16) * 512 + q16, &s_dt[bf][0][0] + (w << 8)); \
        gload16(Ub  + (size_t)(t0_ + r16) * 512 + q16, &s_u [bf][0][0] + (w << 8)); \
        gload16(Zb  + (size_t)(t0_ + r16) * 1024 + q16, &s_z[bf][0][0] + (w << 8)); \
        gload16(DBb + (size_t)(t0_ + r32) * 48 + q32, &s_BC[bf][0][0] + (w << 8)); \
        gload16(DBb + (size_t)(t0_ + 32 + r32) * 48 + q32, &s_BC[bf][0][0] + 1024 + (w << 8)); \
    }

    float h = 0.f;
    int bf = 0;
    STAGE(0, 0);
    __syncthreads();

    for (int c = 0; c < L_SEQ / T_CH; c++) {
        if (c + 1 < L_SEQ / T_CH) STAGE(c + 1, bf ^ 1);
        int yb = c & 1;
        #pragma unroll 1
        for (int tb = 0; tb < 4; tb++) {
            float da[16], db[16], cc[16], uu[16], pr[16];
            #pragma unroll
            for (int j = 0; j < 16; j++) {
                int t = (tb << 4) + j;
                float dtv = s_dt[bf][t][dl];
                float uv  = s_u [bf][t][dl];
                float bs  = s_BC[bf][t][s];
                float cs  = s_BC[bf][t][16 + s];
                da[j] = __expf(dtv * Ads);
                db[j] = dtv * bs * uv;
                cc[j] = cs;
                uu[j] = uv;
            }
            // serial h chain (fma latency only), products off-chain
            #pragma unroll
            for (int j = 0; j < 16; j++) {
                h = fmaf(da[j], h, db[j]);
                pr[j] = h * cc[j];
            }
            // batched 4-level xor reduce over s (16 independent per level -> pipelined)
            #pragma unroll
            for (int j = 0; j < 16; j++) pr[j] += __shfl_xor(pr[j], 1);
            #pragma unroll
            for (int j = 0; j < 16; j++) pr[j] += __shfl_xor(pr[j], 2);
            #pragma unroll
            for (int j = 0; j < 16; j++) pr[j] += __shfl_xor(pr[j], 4);
            #pragma unroll
            for (int j = 0; j < 16; j++) pr[j] += __shfl_xor(pr[j], 8);
            // distribute epilogue: lane s handles t = tb*16 + s (static-index selects)
            float mine = 0.f, myu = 0.f;
            #pragma unroll
            for (int j = 0; j < 16; j++) {
                bool m = (s == j);
                mine = m ? pr[j] : mine;
                myu  = m ? uu[j] : myu;
            }
            int t = (tb << 4) + s;
            float zv = s_z[bf][t][dl];
            float y = mine + myu * Dv;
            s_y[yb][t][dl] = y * (zv / (1.f + __expf(-zv)));
        }
        __syncthreads();
        // bulk store y chunk -> bf16
        {
            int t0_ = c * T_CH;
            float4 v = *(const float4*)(&s_y[yb][0][0] + (tid << 2));
            us4 o;
            o.x = f2b(v.x); o.y = f2b(v.y); o.z = f2b(v.z); o.w = f2b(v.w);
            *(us4*)(Yb + (size_t)(t0_ + r16) * 512 + q16) = o;
        }
        bf ^= 1;
    }
    #undef STAGE
}

extern "C" void kernel_launch(void* const* d_in, const int* in_sizes, int n_in,
                              void* d_out, int out_size, void* d_ws, size_t ws_size,
                              hipStream_t stream) {
    (void)in_sizes; (void)n_in; (void)out_size; (void)ws_size;
    const float* x         = (const float*)d_in[0];
    const float* ln_g      = (const float*)d_in[1];
    const float* ln_b      = (const float*)d_in[2];
    const float* in_proj_w = (const float*)d_in[3];
    const float* conv_w    = (const float*)d_in[4];
    const float* conv_b    = (const float*)d_in[5];
    const float* x_proj_w  = (const float*)d_in[6];
    const float* dt_proj_w = (const float*)d_in[7];
    const float* dt_proj_b = (const float*)d_in[8];
    const float* A_log     = (const float*)d_in[9];
    const float* Dp        = (const float*)d_in[10];
    const float* out_proj_w= (const float*)d_in[11];
    const float* mlp_ln_g  = (const float*)d_in[12];
    const float* mlp_ln_b  = (const float*)d_in[13];
    const float* mlp_w1    = (const float*)d_in[14];
    const float* mlp_b1    = (const float*)d_in[15];
    const float* mlp_w2    = (const float*)d_in[16];
    const float* mlp_b2    = (const float*)d_in[17];

    float* ws  = (float*)d_ws;
    u16*   XNB = (u16*)(ws + OFF_XNB);     // ln1 out (bf16); also ln2 out
    float* XZ  = ws + OFF_XZ;
    u16*   H   = (u16*)(ws + OFF_XZ);      // mlp hidden bf16, aliases XZ (dead after scan)
    float* XC  = ws + OFF_XC;
    float* DBL = ws + OFF_DBL;
    float* DT  = ws + OFF_DT;
    float* XF2 = ws + OFF_XF2;
    u16*   YB  = (u16*)(ws + OFF_YB);
    u16*   WB  = (u16*)(ws + OFF_WB);
    float* out = (float*)d_out;

    // 0. weights -> bf16
    cvt4_kernel<<<3584, 256, 0, stream>>>(in_proj_w, out_proj_w, mlp_w1, mlp_w2, WB);
    // 1. LN1 on transposed x -> XNB (bf16)
    ln_kernel<<<N_TOK, 256, 0, stream>>>(x, ln_g, ln_b, XNB, 1);
    // 2. in_proj: XZ = XNB @ in_proj_w^T  (fp32 out)
    gemm_mfma<0><<<dim3(8, 64), 256, 0, stream>>>(XNB, WB + WB_IN, XZ, N_TOK, 1024, 256, nullptr, nullptr);
    // 3. depthwise conv + silu -> XC (fp32)
    conv_kernel<<<(N_TOK * D_INNER) / 256, 256, 0, stream>>>(XZ, conv_w, conv_b, XC);
    // 4. x_proj + dt_proj + softplus -> DBL, DT
    xproj_kernel<<<N_TOK, 64, 0, stream>>>(XC, x_proj_w, dt_proj_w, dt_proj_b, DBL, DT);
    // 5. selective scan + *silu(z) -> YB (bf16)
    scan_kernel<<<256, 256, 0, stream>>>(XC, DBL, DT, XZ, A_log, Dp, YB);
    // 6. out_proj + residual(x transposed) -> XF2 (fp32)
    gemm_mfma<1><<<dim3(2, 64), 256, 0, stream>>>(YB, WB + WB_OUT, XF2, N_TOK, 256, 512, nullptr, x);
    // 7. LN2 -> XNB (bf16, reuse)
    ln_kernel<<<N_TOK, 256, 0, stream>>>(XF2, mlp_ln_g, mlp_ln_b, XNB, 0);
    // 8. MLP fc1 + bias + gelu -> H (bf16, aliases XZ)
    gemm_mfma<2><<<dim3(8, 64), 256, 0, stream>>>(XNB, WB + WB_W1, H, N_TOK, 1024, 256, mlp_b1, nullptr);
    // 9. MLP fc2 + b2 + residual(XF2), transposed fp32 store -> d_out
    gemm_mfma<3><<<dim3(2, 64), 256, 0, stream>>>(H, WB + WB_W2, out, N_TOK, 256, 1024, mlp_b2, XF2);
}

// Round 5
// 410.738 us; speedup vs baseline: 3.0239x; 1.0863x over previous
//
#include <hip/hip_runtime.h>
#include <math.h>

#define DIM      256
#define L_SEQ    1024
#define B_SZ     8
#define D_INNER  512
#define D_STATE  16
#define DT_RANK  16
#define N_TOK    (B_SZ * L_SEQ)   // 8192

typedef unsigned short u16;
typedef __attribute__((ext_vector_type(4))) float f32x4;
typedef __attribute__((ext_vector_type(8))) short short8;
struct __align__(8) us4 { u16 x, y, z, w; };

// workspace float offsets (~91.5 MB; XCB aliases XNB, H aliases XZ)
#define OFF_XNB  0                     // bf16 8192x256 (LN out) / bf16 8192x512 XCB alias region (1,048,576 fl)
#define OFF_XZ   1048576               // fp32 8192x1024 -> 8,388,608 (also H bf16)
#define OFF_XC   9437184               // fp32 8192x512  -> 4,194,304
#define OFF_DBL  13631488              // fp32 8192x48   ->   393,216
#define OFF_DT   14024704              // fp32 8192x512  -> 4,194,304
#define OFF_XF2  18219008              // fp32 8192x256  -> 2,097,152
#define OFF_YB   20316160              // bf16 8192x512  -> 1,048,576 fl (2,097,152 u16)
#define OFF_WB   22413312              // bf16 weights   -> 471,040 fl (942,080 u16)
// WB sub-offsets in u16 elements
#define WB_IN    0         // 262144
#define WB_OUT   262144    // 131072
#define WB_W1    393216    // 262144
#define WB_W2    655360    // 262144
#define WB_XP    917504    // 24576 (x_proj_w 48x512)

__device__ __forceinline__ u16 f2b(float f) {
    unsigned int u = __float_as_uint(f);
    return (u16)((u + 0x7fffu + ((u >> 16) & 1u)) >> 16);   // RNE
}

// ---------------- weight fp32->bf16 convert (5 segments, one launch) ----------------
__global__ __launch_bounds__(256) void cvt5_kernel(const float* __restrict__ a,
                                                   const float* __restrict__ b,
                                                   const float* __restrict__ c,
                                                   const float* __restrict__ d,
                                                   const float* __restrict__ e,
                                                   u16* __restrict__ out) {
    int i = blockIdx.x * 256 + threadIdx.x;   // total 942080
    const float* src; int off;
    if (i < 262144)      { src = a; off = i; }
    else if (i < 393216) { src = b; off = i - 262144; }
    else if (i < 655360) { src = c; off = i - 393216; }
    else if (i < 917504) { src = d; off = i - 655360; }
    else                 { src = e; off = i - 917504; }
    out[i] = f2b(src[off]);
}

// ---------------- LayerNorm over C=256, one block per token; bf16 out ----------------
__global__ __launch_bounds__(256) void ln_kernel(const float* __restrict__ in,
                                                 const float* __restrict__ g,
                                                 const float* __restrict__ b,
                                                 u16* __restrict__ out,
                                                 int transposed_in) {
    int token = blockIdx.x;
    int c = threadIdx.x;
    float v;
    if (transposed_in) {
        int bb = token >> 10, l = token & 1023;
        v = in[((size_t)bb * DIM + c) * L_SEQ + l];
    } else {
        v = in[(size_t)token * DIM + c];
    }
    float s = v, s2 = v * v;
    #pragma unroll
    for (int o = 32; o; o >>= 1) {
        s  += __shfl_down(s, o);
        s2 += __shfl_down(s2, o);
    }
    __shared__ float red[8];
    int w = threadIdx.x >> 6;
    if ((threadIdx.x & 63) == 0) { red[w] = s; red[4 + w] = s2; }
    __syncthreads();
    if (threadIdx.x == 0) {
        float a = 0.f, aa = 0.f;
        for (int i = 0; i < 4; i++) { a += red[i]; aa += red[4 + i]; }
        red[0] = a; red[4] = aa;
    }
    __syncthreads();
    float mean = red[0] * (1.f / DIM);
    float var  = red[4] * (1.f / DIM) - mean * mean;
    float rstd = rsqrtf(var + 1e-5f);
    out[(size_t)token * DIM + c] = f2b((v - mean) * rstd * g[c] + b[c]);
}

// ---------------- global->LDS async helper (16B) ----------------
__device__ __forceinline__ void gload16(const void* g, void* l) {
    __builtin_amdgcn_global_load_lds(
        (const __attribute__((address_space(1))) unsigned int*)g,
        (__attribute__((address_space(3))) unsigned int*)l,
        16, 0, 0);
}

// ---------------- bf16 MFMA GEMM: C[M,N] = A[M,K] @ W[N,K]^T ----------------
// 128x128 tile, BK=32, 4 waves (2x2), each wave 64x64 = 4x4 frags of 16x16x32.
template <int EPI>
__global__ __launch_bounds__(256) void gemm_mfma(const u16* __restrict__ A,
                                                 const u16* __restrict__ W,
                                                 void* __restrict__ Cout,
                                                 int M, int N, int K,
                                                 const float* __restrict__ bias,
                                                 const float* __restrict__ extra) {
    __shared__ u16 Als[4096];   // [128][32] bf16, row-major
    __shared__ u16 Bls[4096];
    int tid = threadIdx.x;
    int w = tid >> 6, l = tid & 63;
    int m0 = blockIdx.y << 7, n0 = blockIdx.x << 7;

    int srow = tid >> 2;
    int scol = (tid & 3) << 3;
    const u16* Ag  = A + (size_t)(m0 + srow) * K + scol;
    const u16* Ag2 = A + (size_t)(m0 + 64 + srow) * K + scol;
    const u16* Wg  = W + (size_t)(n0 + srow) * K + scol;
    const u16* Wg2 = W + (size_t)(n0 + 64 + srow) * K + scol;
    u16* Ab0 = Als + (w << 9);
    u16* Ab1 = Als + 2048 + (w << 9);
    u16* Bb0 = Bls + (w << 9);
    u16* Bb1 = Bls + 2048 + (w << 9);

    int wr = (w >> 1) << 6, wc = (w & 1) << 6;
    int fr = l & 15, fk = (l >> 4) << 3;

    f32x4 acc[4][4] = {};
    for (int k0 = 0; k0 < K; k0 += 32) {
        gload16(Ag + k0, Ab0);
        gload16(Ag2 + k0, Ab1);
        gload16(Wg + k0, Bb0);
        gload16(Wg2 + k0, Bb1);
        __syncthreads();
        short8 af[4], bfr[4];
        #pragma unroll
        for (int i = 0; i < 4; i++)
            af[i] = *(const short8*)&Als[(wr + i * 16 + fr) * 32 + fk];
        #pragma unroll
        for (int j = 0; j < 4; j++)
            bfr[j] = *(const short8*)&Bls[(wc + j * 16 + fr) * 32 + fk];
        #pragma unroll
        for (int i = 0; i < 4; i++)
            #pragma unroll
            for (int j = 0; j < 4; j++)
                acc[i][j] = __builtin_amdgcn_mfma_f32_16x16x32_bf16(af[i], bfr[j], acc[i][j], 0, 0, 0);
        __syncthreads();
    }

    int cr = (l >> 4) << 2;
    int ccol = l & 15;
    #pragma unroll
    for (int i = 0; i < 4; i++) {
        #pragma unroll
        for (int j = 0; j < 4; j++) {
            int n = n0 + wc + j * 16 + ccol;
            #pragma unroll
            for (int r = 0; r < 4; r++) {
                int m = m0 + wr + i * 16 + cr + r;
                int bb = m >> 10, ll = m & 1023;
                float v = acc[i][j][r];
                if (EPI == 0) {
                    ((float*)Cout)[(size_t)m * N + n] = v;
                } else if (EPI == 1) {
                    ((float*)Cout)[(size_t)m * N + n] = v + extra[((size_t)bb * DIM + n) * L_SEQ + ll];
                } else if (EPI == 2) {
                    v += bias[n];
                    ((u16*)Cout)[(size_t)m * N + n] = f2b(0.5f * v * (1.f + erff(v * 0.70710678118f)));
                } else {
                    v += bias[n] + extra[(size_t)m * DIM + n];
                    ((float*)Cout)[((size_t)bb * DIM + n) * L_SEQ + ll] = v;
                }
            }
        }
    }
}

// ---------------- depthwise causal conv (k=4) + silu; fp32 + bf16 out ----------------
__global__ __launch_bounds__(256) void conv_kernel(const float* __restrict__ XZ,
                                                   const float* __restrict__ cw,
                                                   const float* __restrict__ cb,
                                                   float* __restrict__ XC,
                                                   u16* __restrict__ XCB) {
    int idx = blockIdx.x * 256 + threadIdx.x;
    int d = idx & 511;
    int token = idx >> 9;
    int l = token & 1023, b = token >> 10;
    const float* base = XZ + (size_t)b * L_SEQ * 1024 + d;
    float acc = cb[d];
    #pragma unroll
    for (int j = 0; j < 4; j++) {
        int ls = l - 3 + j;
        if (ls >= 0) acc = fmaf(base[(size_t)ls * 1024], cw[d * 4 + j], acc);
    }
    float v = acc / (1.f + __expf(-acc));
    XC[(size_t)token * 512 + d] = v;
    XCB[(size_t)token * 512 + d] = f2b(v);
}

// ---------------- xproj v2: MFMA x_proj + fused fp32 dt_proj + softplus ----------------
// 64 blocks x 256 threads; block = 128 tokens. Wave w: rows w*32..+31 (2 frags) x 48 cols (3 frags).
// Frags loaded direct from global (L2-hot, no reuse). dt_proj fp32 with LDS-broadcast weights.
__global__ __launch_bounds__(256) void xproj2_kernel(const u16* __restrict__ XCB,
                                                     const u16* __restrict__ WXP,
                                                     const float* __restrict__ dt_proj_w,
                                                     const float* __restrict__ dt_proj_b,
                                                     float* __restrict__ DBL,
                                                     float* __restrict__ DT) {
    __shared__ float dbl_s[128][49];   // +1 pad
    __shared__ float wdt[8192];        // dt_proj_w [512][16]
    __shared__ float wdb[512];
    int tid = threadIdx.x;
    int w = tid >> 6, l = tid & 63;
    int m0 = blockIdx.x << 7;

    // stage dt weights (coalesced, linear); consumed after the dbl_s barrier
    #pragma unroll
    for (int k = 0; k < 32; k++) wdt[tid + (k << 8)] = dt_proj_w[tid + (k << 8)];
    wdb[tid] = dt_proj_b[tid];
    wdb[tid + 256] = dt_proj_b[tid + 256];

    // --- x_proj GEMM: [128 x 48] = XCB[128 x 512] @ WXP[48 x 512]^T ---
    int fr = l & 15, fk = (l >> 4) << 3;
    const u16* Ab = XCB + (size_t)(m0 + (w << 5) + fr) * 512 + fk;
    const u16* Wb = WXP + (size_t)fr * 512 + fk;
    f32x4 acc[2][3] = {};
    for (int k0 = 0; k0 < 512; k0 += 32) {
        short8 a0 = *(const short8*)(Ab + k0);
        short8 a1 = *(const short8*)(Ab + (16 * 512) + k0);
        short8 b0 = *(const short8*)(Wb + k0);
        short8 b1 = *(const short8*)(Wb + (16 * 512) + k0);
        short8 b2 = *(const short8*)(Wb + (32 * 512) + k0);
        acc[0][0] = __builtin_amdgcn_mfma_f32_16x16x32_bf16(a0, b0, acc[0][0], 0, 0, 0);
        acc[0][1] = __builtin_amdgcn_mfma_f32_16x16x32_bf16(a0, b1, acc[0][1], 0, 0, 0);
        acc[0][2] = __builtin_amdgcn_mfma_f32_16x16x32_bf16(a0, b2, acc[0][2], 0, 0, 0);
        acc[1][0] = __builtin_amdgcn_mfma_f32_16x16x32_bf16(a1, b0, acc[1][0], 0, 0, 0);
        acc[1][1] = __builtin_amdgcn_mfma_f32_16x16x32_bf16(a1, b1, acc[1][1], 0, 0, 0);
        acc[1][2] = __builtin_amdgcn_mfma_f32_16x16x32_bf16(a1, b2, acc[1][2], 0, 0, 0);
    }
    // C/D: col = l&15, row = (l>>4)*4 + r
    int cr = (l >> 4) << 2, ccol = l & 15;
    #pragma unroll
    for (int i = 0; i < 2; i++)
        #pragma unroll
        for (int j = 0; j < 3; j++)
            #pragma unroll
            for (int r = 0; r < 4; r++)
                dbl_s[(w << 5) + i * 16 + cr + r][j * 16 + ccol] = acc[i][j][r];
    __syncthreads();

    // export B,C (cols 16..47) to DBL for the scan
    {
        int t = tid >> 1, c0 = 16 + ((tid & 1) << 4);
        float* dst = DBL + (size_t)(m0 + t) * 48 + c0;
        #pragma unroll
        for (int k = 0; k < 16; k++) dst[k] = dbl_s[t][c0 + k];
    }

    // --- dt_proj fp32: dt[t][d] = softplus(dtr . wdt[d] + b[d]) ---
    int t = tid >> 1, half = tid & 1;
    float dtr[16];
    #pragma unroll
    for (int r = 0; r < 16; r++) dtr[r] = dbl_s[t][r];
    float* dout = DT + (size_t)(m0 + t) * 512 + (half << 8);
    for (int dd = 0; dd < 256; dd += 4) {
        float4 ov;
        #pragma unroll
        for (int q = 0; q < 4; q++) {
            int d = (half << 8) + dd + q;
            const float4* wr = (const float4*)&wdt[d << 4];
            float4 w0 = wr[0], w1 = wr[1], w2 = wr[2], w3 = wr[3];
            float a = wdb[d];
            a += dtr[0] * w0.x + dtr[1] * w0.y + dtr[2] * w0.z + dtr[3] * w0.w;
            a += dtr[4] * w1.x + dtr[5] * w1.y + dtr[6] * w1.z + dtr[7] * w1.w;
            a += dtr[8] * w2.x + dtr[9] * w2.y + dtr[10] * w2.z + dtr[11] * w2.w;
            a += dtr[12] * w3.x + dtr[13] * w3.y + dtr[14] * w3.z + dtr[15] * w3.w;
            float sp = (a > 20.f) ? a : log1pf(__expf(a));
            ((float*)&ov)[q] = sp;
        }
        *(float4*)(dout + dd) = ov;
    }
}

// ---------------- selective scan v3: batched shuffle reduce, bf16 y out ----------------
#define T_CH 64
__global__ __launch_bounds__(256) void scan_kernel(const float* __restrict__ U,
                                                   const float* __restrict__ DBL,
                                                   const float* __restrict__ DT,
                                                   const float* __restrict__ XZ,
                                                   const float* __restrict__ A_log,
                                                   const float* __restrict__ Dp,
                                                   u16* __restrict__ YB) {
    __shared__ float s_dt[2][T_CH][16];
    __shared__ float s_u [2][T_CH][16];
    __shared__ float s_BC[2][T_CH][32];
    __shared__ float s_z [2][T_CH][16];
    __shared__ float s_y [2][T_CH][16];

    int blk = blockIdx.x;
    int b = blk >> 5, ch = blk & 31;
    int tid = threadIdx.x;
    int s = tid & 15, dl = tid >> 4;
    int d = ch * 16 + dl;
    int w = tid >> 6;

    float Ads = -__expf(A_log[d * D_STATE + s]);
    float Dv = Dp[d];

    const float* DTb = DT  + (size_t)b * L_SEQ * D_INNER + ch * 16;
    const float* Ub  = U   + (size_t)b * L_SEQ * D_INNER + ch * 16;
    const float* DBb = DBL + (size_t)b * L_SEQ * 48 + 16;
    const float* Zb  = XZ  + (size_t)b * L_SEQ * 1024 + 512 + ch * 16;
    u16* Yb          = YB  + (size_t)b * L_SEQ * D_INNER + ch * 16;

    int r16 = tid >> 2, q16 = (tid & 3) << 2;
    int r32 = tid >> 3, q32 = (tid & 7) << 2;

    #define STAGE(c, bf) { \
        int t0_ = (c) * T_CH; \
        gload16(DTb + (size_t)(t0_ + r16) * 512 + q16, &s_dt[bf][0][0] + (w << 8)); \
        gload16(Ub  + (size_t)(t0_ + r16) * 512 + q16, &s_u [bf][0][0] + (w << 8)); \
        gload16(Zb  + (size_t)(t0_ + r16) * 1024 + q16, &s_z[bf][0][0] + (w << 8)); \
        gload16(DBb + (size_t)(t0_ + r32) * 48 + q32, &s_BC[bf][0][0] + (w << 8)); \
        gload16(DBb + (size_t)(t0_ + 32 + r32) * 48 + q32, &s_BC[bf][0][0] + 1024 + (w << 8)); \
    }

    float h = 0.f;
    int bf = 0;
    STAGE(0, 0);
    __syncthreads();

    for (int c = 0; c < L_SEQ / T_CH; c++) {
        if (c + 1 < L_SEQ / T_CH) STAGE(c + 1, bf ^ 1);
        int yb = c & 1;
        #pragma unroll 1
        for (int tb = 0; tb < 4; tb++) {
            float da[16], db[16], cc[16], uu[16], pr[16];
            #pragma unroll
            for (int j = 0; j < 16; j++) {
                int t = (tb << 4) + j;
                float dtv = s_dt[bf][t][dl];
                float uv  = s_u [bf][t][dl];
                float bs  = s_BC[bf][t][s];
                float cs  = s_BC[bf][t][16 + s];
                da[j] = __expf(dtv * Ads);
                db[j] = dtv * bs * uv;
                cc[j] = cs;
                uu[j] = uv;
            }
            #pragma unroll
            for (int j = 0; j < 16; j++) {
                h = fmaf(da[j], h, db[j]);
                pr[j] = h * cc[j];
            }
            #pragma unroll
            for (int j = 0; j < 16; j++) pr[j] += __shfl_xor(pr[j], 1);
            #pragma unroll
            for (int j = 0; j < 16; j++) pr[j] += __shfl_xor(pr[j], 2);
            #pragma unroll
            for (int j = 0; j < 16; j++) pr[j] += __shfl_xor(pr[j], 4);
            #pragma unroll
            for (int j = 0; j < 16; j++) pr[j] += __shfl_xor(pr[j], 8);
            float mine = 0.f, myu = 0.f;
            #pragma unroll
            for (int j = 0; j < 16; j++) {
                bool m = (s == j);
                mine = m ? pr[j] : mine;
                myu  = m ? uu[j] : myu;
            }
            int t = (tb << 4) + s;
            float zv = s_z[bf][t][dl];
            float y = mine + myu * Dv;
            s_y[yb][t][dl] = y * (zv / (1.f + __expf(-zv)));
        }
        __syncthreads();
        {
            int t0_ = c * T_CH;
            float4 v = *(const float4*)(&s_y[yb][0][0] + (tid << 2));
            us4 o;
            o.x = f2b(v.x); o.y = f2b(v.y); o.z = f2b(v.z); o.w = f2b(v.w);
            *(us4*)(Yb + (size_t)(t0_ + r16) * 512 + q16) = o;
        }
        bf ^= 1;
    }
    #undef STAGE
}

extern "C" void kernel_launch(void* const* d_in, const int* in_sizes, int n_in,
                              void* d_out, int out_size, void* d_ws, size_t ws_size,
                              hipStream_t stream) {
    (void)in_sizes; (void)n_in; (void)out_size; (void)ws_size;
    const float* x         = (const float*)d_in[0];
    const float* ln_g      = (const float*)d_in[1];
    const float* ln_b      = (const float*)d_in[2];
    const float* in_proj_w = (const float*)d_in[3];
    const float* conv_w    = (const float*)d_in[4];
    const float* conv_b    = (const float*)d_in[5];
    const float* x_proj_w  = (const float*)d_in[6];
    const float* dt_proj_w = (const float*)d_in[7];
    const float* dt_proj_b = (const float*)d_in[8];
    const float* A_log     = (const float*)d_in[9];
    const float* Dp        = (const float*)d_in[10];
    const float* out_proj_w= (const float*)d_in[11];
    const float* mlp_ln_g  = (const float*)d_in[12];
    const float* mlp_ln_b  = (const float*)d_in[13];
    const float* mlp_w1    = (const float*)d_in[14];
    const float* mlp_b1    = (const float*)d_in[15];
    const float* mlp_w2    = (const float*)d_in[16];
    const float* mlp_b2    = (const float*)d_in[17];

    float* ws  = (float*)d_ws;
    u16*   XNB = (u16*)(ws + OFF_XNB);     // LN out (bf16); also XCB alias
    u16*   XCB = (u16*)(ws + OFF_XNB);     // conv out bf16 (XNB dead after in_proj)
    float* XZ  = ws + OFF_XZ;
    u16*   H   = (u16*)(ws + OFF_XZ);      // mlp hidden bf16, aliases XZ
    float* XC  = ws + OFF_XC;
    float* DBL = ws + OFF_DBL;
    float* DT  = ws + OFF_DT;
    float* XF2 = ws + OFF_XF2;
    u16*   YB  = (u16*)(ws + OFF_YB);
    u16*   WB  = (u16*)(ws + OFF_WB);
    float* out = (float*)d_out;

    // 0. weights -> bf16
    cvt5_kernel<<<3680, 256, 0, stream>>>(in_proj_w, out_proj_w, mlp_w1, mlp_w2, x_proj_w, WB);
    // 1. LN1 on transposed x -> XNB (bf16)
    ln_kernel<<<N_TOK, 256, 0, stream>>>(x, ln_g, ln_b, XNB, 1);
    // 2. in_proj: XZ = XNB @ in_proj_w^T  (fp32 out)
    gemm_mfma<0><<<dim3(8, 64), 256, 0, stream>>>(XNB, WB + WB_IN, XZ, N_TOK, 1024, 256, nullptr, nullptr);
    // 3. depthwise conv + silu -> XC (fp32) + XCB (bf16, overwrites XNB region)
    conv_kernel<<<(N_TOK * D_INNER) / 256, 256, 0, stream>>>(XZ, conv_w, conv_b, XC, XCB);
    // 4. x_proj (MFMA) + dt_proj + softplus -> DBL (cols 16..47), DT
    xproj2_kernel<<<64, 256, 0, stream>>>(XCB, WB + WB_XP, dt_proj_w, dt_proj_b, DBL, DT);
    // 5. selective scan + *silu(z) -> YB (bf16)
    scan_kernel<<<256, 256, 0, stream>>>(XC, DBL, DT, XZ, A_log, Dp, YB);
    // 6. out_proj + residual(x transposed) -> XF2 (fp32)
    gemm_mfma<1><<<dim3(2, 64), 256, 0, stream>>>(YB, WB + WB_OUT, XF2, N_TOK, 256, 512, nullptr, x);
    // 7. LN2 -> XNB (bf16, reuse)
    ln_kernel<<<N_TOK, 256, 0, stream>>>(XF2, mlp_ln_g, mlp_ln_b, XNB, 0);
    // 8. MLP fc1 + bias + gelu -> H (bf16, aliases XZ)
    gemm_mfma<2><<<dim3(8, 64), 256, 0, stream>>>(XNB, WB + WB_W1, H, N_TOK, 1024, 256, mlp_b1, nullptr);
    // 9. MLP fc2 + b2 + residual(XF2), transposed fp32 store -> d_out
    gemm_mfma<3><<<dim3(2, 64), 256, 0, stream>>>(H, WB + WB_W2, out, N_TOK, 256, 1024, mlp_b2, XF2);
}

// Round 6
// 331.958 us; speedup vs baseline: 3.7415x; 1.2373x over previous
//
#include <hip/hip_runtime.h>
#include <math.h>

#define DIM      256
#define L_SEQ    1024
#define B_SZ     8
#define D_INNER  512
#define D_STATE  16
#define DT_RANK  16
#define N_TOK    (B_SZ * L_SEQ)   // 8192

typedef unsigned short u16;
typedef __attribute__((ext_vector_type(4))) float f32x4;
typedef __attribute__((ext_vector_type(8))) short short8;
struct __align__(8) us4 { u16 x, y, z, w; };

// workspace float offsets (~91.5 MB; XCB aliases XNB, H aliases XZ)
#define OFF_XNB  0                     // bf16 LN out / XCB alias (1,048,576 fl)
#define OFF_XZ   1048576               // fp32 8192x1024 -> 8,388,608 (also H bf16)
#define OFF_XC   9437184               // fp32 8192x512  -> 4,194,304
#define OFF_DBL  13631488              // fp32 8192x48   ->   393,216
#define OFF_DT   14024704              // fp32 8192x512  -> 4,194,304
#define OFF_XF2  18219008              // fp32 8192x256  -> 2,097,152
#define OFF_YB   20316160              // bf16 8192x512  -> 1,048,576 fl
#define OFF_WB   22413312              // bf16 weights
// WB sub-offsets in u16 elements
#define WB_IN    0
#define WB_OUT   262144
#define WB_W1    393216
#define WB_W2    655360
#define WB_XP    917504    // x_proj_w 48x512

__device__ __forceinline__ u16 f2b(float f) {
    unsigned int u = __float_as_uint(f);
    return (u16)((u + 0x7fffu + ((u >> 16) & 1u)) >> 16);   // RNE
}

// ---------------- weight fp32->bf16 convert (5 segments, one launch) ----------------
__global__ __launch_bounds__(256) void cvt5_kernel(const float* __restrict__ a,
                                                   const float* __restrict__ b,
                                                   const float* __restrict__ c,
                                                   const float* __restrict__ d,
                                                   const float* __restrict__ e,
                                                   u16* __restrict__ out) {
    int i = blockIdx.x * 256 + threadIdx.x;   // total 942080
    const float* src; int off;
    if (i < 262144)      { src = a; off = i; }
    else if (i < 393216) { src = b; off = i - 262144; }
    else if (i < 655360) { src = c; off = i - 393216; }
    else if (i < 917504) { src = d; off = i - 655360; }
    else                 { src = e; off = i - 917504; }
    out[i] = f2b(src[off]);
}

// ---------------- LayerNorm over C=256, one block per token; bf16 out ----------------
__global__ __launch_bounds__(256) void ln_kernel(const float* __restrict__ in,
                                                 const float* __restrict__ g,
                                                 const float* __restrict__ b,
                                                 u16* __restrict__ out,
                                                 int transposed_in) {
    int token = blockIdx.x;
    int c = threadIdx.x;
    float v;
    if (transposed_in) {
        int bb = token >> 10, l = token & 1023;
        v = in[((size_t)bb * DIM + c) * L_SEQ + l];
    } else {
        v = in[(size_t)token * DIM + c];
    }
    float s = v, s2 = v * v;
    #pragma unroll
    for (int o = 32; o; o >>= 1) {
        s  += __shfl_down(s, o);
        s2 += __shfl_down(s2, o);
    }
    __shared__ float red[8];
    int w = threadIdx.x >> 6;
    if ((threadIdx.x & 63) == 0) { red[w] = s; red[4 + w] = s2; }
    __syncthreads();
    if (threadIdx.x == 0) {
        float a = 0.f, aa = 0.f;
        for (int i = 0; i < 4; i++) { a += red[i]; aa += red[4 + i]; }
        red[0] = a; red[4] = aa;
    }
    __syncthreads();
    float mean = red[0] * (1.f / DIM);
    float var  = red[4] * (1.f / DIM) - mean * mean;
    float rstd = rsqrtf(var + 1e-5f);
    out[(size_t)token * DIM + c] = f2b((v - mean) * rstd * g[c] + b[c]);
}

// ---------------- global->LDS async helper (16B) ----------------
__device__ __forceinline__ void gload16(const void* g, void* l) {
    __builtin_amdgcn_global_load_lds(
        (const __attribute__((address_space(1))) unsigned int*)g,
        (__attribute__((address_space(3))) unsigned int*)l,
        16, 0, 0);
}

// ---------------- bf16 MFMA GEMM: C[M,N] = A[M,K] @ W[N,K]^T ----------------
template <int EPI>
__global__ __launch_bounds__(256) void gemm_mfma(const u16* __restrict__ A,
                                                 const u16* __restrict__ W,
                                                 void* __restrict__ Cout,
                                                 int M, int N, int K,
                                                 const float* __restrict__ bias,
                                                 const float* __restrict__ extra) {
    __shared__ u16 Als[4096];   // [128][32] bf16, row-major
    __shared__ u16 Bls[4096];
    int tid = threadIdx.x;
    int w = tid >> 6, l = tid & 63;
    int m0 = blockIdx.y << 7, n0 = blockIdx.x << 7;

    int srow = tid >> 2;
    int scol = (tid & 3) << 3;
    const u16* Ag  = A + (size_t)(m0 + srow) * K + scol;
    const u16* Ag2 = A + (size_t)(m0 + 64 + srow) * K + scol;
    const u16* Wg  = W + (size_t)(n0 + srow) * K + scol;
    const u16* Wg2 = W + (size_t)(n0 + 64 + srow) * K + scol;
    u16* Ab0 = Als + (w << 9);
    u16* Ab1 = Als + 2048 + (w << 9);
    u16* Bb0 = Bls + (w << 9);
    u16* Bb1 = Bls + 2048 + (w << 9);

    int wr = (w >> 1) << 6, wc = (w & 1) << 6;
    int fr = l & 15, fk = (l >> 4) << 3;

    f32x4 acc[4][4] = {};
    for (int k0 = 0; k0 < K; k0 += 32) {
        gload16(Ag + k0, Ab0);
        gload16(Ag2 + k0, Ab1);
        gload16(Wg + k0, Bb0);
        gload16(Wg2 + k0, Bb1);
        __syncthreads();
        short8 af[4], bfr[4];
        #pragma unroll
        for (int i = 0; i < 4; i++)
            af[i] = *(const short8*)&Als[(wr + i * 16 + fr) * 32 + fk];
        #pragma unroll
        for (int j = 0; j < 4; j++)
            bfr[j] = *(const short8*)&Bls[(wc + j * 16 + fr) * 32 + fk];
        #pragma unroll
        for (int i = 0; i < 4; i++)
            #pragma unroll
            for (int j = 0; j < 4; j++)
                acc[i][j] = __builtin_amdgcn_mfma_f32_16x16x32_bf16(af[i], bfr[j], acc[i][j], 0, 0, 0);
        __syncthreads();
    }

    int cr = (l >> 4) << 2;
    int ccol = l & 15;
    #pragma unroll
    for (int i = 0; i < 4; i++) {
        #pragma unroll
        for (int j = 0; j < 4; j++) {
            int n = n0 + wc + j * 16 + ccol;
            #pragma unroll
            for (int r = 0; r < 4; r++) {
                int m = m0 + wr + i * 16 + cr + r;
                int bb = m >> 10, ll = m & 1023;
                float v = acc[i][j][r];
                if (EPI == 0) {
                    ((float*)Cout)[(size_t)m * N + n] = v;
                } else if (EPI == 1) {
                    ((float*)Cout)[(size_t)m * N + n] = v + extra[((size_t)bb * DIM + n) * L_SEQ + ll];
                } else if (EPI == 2) {
                    v += bias[n];
                    ((u16*)Cout)[(size_t)m * N + n] = f2b(0.5f * v * (1.f + erff(v * 0.70710678118f)));
                } else {
                    v += bias[n] + extra[(size_t)m * DIM + n];
                    ((float*)Cout)[((size_t)bb * DIM + n) * L_SEQ + ll] = v;
                }
            }
        }
    }
}

// ---------------- depthwise causal conv (k=4) + silu; fp32 + bf16 out ----------------
__global__ __launch_bounds__(256) void conv_kernel(const float* __restrict__ XZ,
                                                   const float* __restrict__ cw,
                                                   const float* __restrict__ cb,
                                                   float* __restrict__ XC,
                                                   u16* __restrict__ XCB) {
    int idx = blockIdx.x * 256 + threadIdx.x;
    int d = idx & 511;
    int token = idx >> 9;
    int l = token & 1023, b = token >> 10;
    const float* base = XZ + (size_t)b * L_SEQ * 1024 + d;
    float acc = cb[d];
    #pragma unroll
    for (int j = 0; j < 4; j++) {
        int ls = l - 3 + j;
        if (ls >= 0) acc = fmaf(base[(size_t)ls * 1024], cw[d * 4 + j], acc);
    }
    float v = acc / (1.f + __expf(-acc));
    XC[(size_t)token * 512 + d] = v;
    XCB[(size_t)token * 512 + d] = f2b(v);
}

// ---------------- xproj v3: MFMA x_proj only, 256 blocks x 32 tokens ----------------
// 128 threads = 2 waves; wave w: rows w*16..+15, 3 col-frags (48 cols). Direct-global frags.
// Exports ALL 48 cols (dtr 0..15 for dtproj_kernel, B/C 16..47 for scan).
__global__ __launch_bounds__(128) void xproj3_kernel(const u16* __restrict__ XCB,
                                                     const u16* __restrict__ WXP,
                                                     float* __restrict__ DBL) {
    __shared__ float dbl_s[32][49];
    int tid = threadIdx.x;
    int w = tid >> 6, l = tid & 63;
    int m0 = blockIdx.x << 5;
    int fr = l & 15, fk = (l >> 4) << 3;
    const u16* Ab = XCB + (size_t)(m0 + (w << 4) + fr) * 512 + fk;
    const u16* Wb = WXP + (size_t)fr * 512 + fk;
    f32x4 acc[3] = {};
    for (int k0 = 0; k0 < 512; k0 += 32) {
        short8 a0 = *(const short8*)(Ab + k0);
        short8 b0 = *(const short8*)(Wb + k0);
        short8 b1 = *(const short8*)(Wb + 16 * 512 + k0);
        short8 b2 = *(const short8*)(Wb + 32 * 512 + k0);
        acc[0] = __builtin_amdgcn_mfma_f32_16x16x32_bf16(a0, b0, acc[0], 0, 0, 0);
        acc[1] = __builtin_amdgcn_mfma_f32_16x16x32_bf16(a0, b1, acc[1], 0, 0, 0);
        acc[2] = __builtin_amdgcn_mfma_f32_16x16x32_bf16(a0, b2, acc[2], 0, 0, 0);
    }
    int cr = (l >> 4) << 2, ccol = l & 15;
    #pragma unroll
    for (int j = 0; j < 3; j++)
        #pragma unroll
        for (int r = 0; r < 4; r++)
            dbl_s[(w << 4) + cr + r][j * 16 + ccol] = acc[j][r];
    __syncthreads();
    // export 32x48 floats as float4s (1536 = 3 * 128 * 4)
    #pragma unroll
    for (int it = 0; it < 3; it++) {
        int fidx = it * 512 + tid * 4;
        int row = fidx / 48, col = fidx % 48;
        float4 v;
        v.x = dbl_s[row][col]; v.y = dbl_s[row][col + 1];
        v.z = dbl_s[row][col + 2]; v.w = dbl_s[row][col + 3];
        *(float4*)(DBL + (size_t)(m0 + row) * 48 + col) = v;
    }
}

// ---------------- dt_proj + softplus: wide memory-bound kernel ----------------
// thread -> one float4 of DT[8192][512]. 4096 blocks x 256 threads.
__global__ __launch_bounds__(256) void dtproj_kernel(const float* __restrict__ DBL,
                                                     const float* __restrict__ wdt,
                                                     const float* __restrict__ wdb,
                                                     float* __restrict__ DT) {
    int idx = blockIdx.x * 256 + threadIdx.x;
    int token = idx >> 7, q = idx & 127;
    int d0 = q << 2;
    const float4* dtr4 = (const float4*)(DBL + (size_t)token * 48);
    float4 t0 = dtr4[0], t1 = dtr4[1], t2 = dtr4[2], t3 = dtr4[3];
    float4 ov;
    #pragma unroll
    for (int qq = 0; qq < 4; qq++) {
        int d = d0 + qq;
        const float4* wr = (const float4*)(wdt + (size_t)d * 16);
        float4 w0 = wr[0], w1 = wr[1], w2 = wr[2], w3 = wr[3];
        float a = wdb[d];
        a += t0.x * w0.x + t0.y * w0.y + t0.z * w0.z + t0.w * w0.w;
        a += t1.x * w1.x + t1.y * w1.y + t1.z * w1.z + t1.w * w1.w;
        a += t2.x * w2.x + t2.y * w2.y + t2.z * w2.z + t2.w * w2.w;
        a += t3.x * w3.x + t3.y * w3.y + t3.z * w3.z + t3.w * w3.w;
        ((float*)&ov)[qq] = (a > 20.f) ? a : log1pf(__expf(a));
    }
    *(float4*)(DT + (size_t)token * 512 + d0) = ov;
}

// ---------------- selective scan v4: transpose-reduce (15 shuffles/16 steps) ----------------
#define T_CH 64
__global__ __launch_bounds__(256) void scan_kernel(const float* __restrict__ U,
                                                   const float* __restrict__ DBL,
                                                   const float* __restrict__ DT,
                                                   const float* __restrict__ XZ,
                                                   const float* __restrict__ A_log,
                                                   const float* __restrict__ Dp,
                                                   u16* __restrict__ YB) {
    __shared__ float s_dt[2][T_CH][16];
    __shared__ float s_u [2][T_CH][16];
    __shared__ float s_BC[2][T_CH][32];
    __shared__ float s_z [2][T_CH][16];
    __shared__ float s_y [2][T_CH * 17];   // padded stride 17 (bank-conflict fix)

    int blk = blockIdx.x;
    int b = blk >> 5, ch = blk & 31;
    int tid = threadIdx.x;
    int s = tid & 15, dl = tid >> 4;
    int d = ch * 16 + dl;
    int w = tid >> 6;

    float Ads = -__expf(A_log[d * D_STATE + s]);
    float Dv = Dp[d];

    const float* DTb = DT  + (size_t)b * L_SEQ * D_INNER + ch * 16;
    const float* Ub  = U   + (size_t)b * L_SEQ * D_INNER + ch * 16;
    const float* DBb = DBL + (size_t)b * L_SEQ * 48 + 16;
    const float* Zb  = XZ  + (size_t)b * L_SEQ * 1024 + 512 + ch * 16;
    u16* Yb          = YB  + (size_t)b * L_SEQ * D_INNER + ch * 16;

    int r16 = tid >> 2, q16 = (tid & 3) << 2;
    int r32 = tid >> 3, q32 = (tid & 7) << 2;

    #define STAGE(c, bf) { \
        int t0_ = (c) * T_CH; \
        gload16(DTb + (size_t)(t0_ + r16) * 512 + q16, &s_dt[bf][0][0] + (w << 8)); \
        gload16(Ub  + (size_t)(t0_ + r16) * 512 + q16, &s_u [bf][0][0] + (w << 8)); \
        gload16(Zb  + (size_t)(t0_ + r16) * 1024 + q16, &s_z[bf][0][0] + (w << 8)); \
        gload16(DBb + (size_t)(t0_ + r32) * 48 + q32, &s_BC[bf][0][0] + (w << 8)); \
        gload16(DBb + (size_t)(t0_ + 32 + r32) * 48 + q32, &s_BC[bf][0][0] + 1024 + (w << 8)); \
    }

    float h = 0.f;
    int bf = 0;
    STAGE(0, 0);
    __syncthreads();

    for (int c = 0; c < L_SEQ / T_CH; c++) {
        if (c + 1 < L_SEQ / T_CH) STAGE(c + 1, bf ^ 1);
        int yb = c & 1;
        #pragma unroll 1
        for (int tb = 0; tb < 4; tb++) {
            float da[16], db[16], cc[16], pr[16];
            float myud = 0.f;
            #pragma unroll
            for (int j = 0; j < 16; j++) {
                int t = (tb << 4) + j;
                float dtv = s_dt[bf][t][dl];
                float uv  = s_u [bf][t][dl];
                float bs  = s_BC[bf][t][s];
                float cs  = s_BC[bf][t][16 + s];
                da[j] = __expf(dtv * Ads);
                db[j] = dtv * bs * uv;
                cc[j] = cs;
                myud = (s == j) ? uv * Dv : myud;   // u*D for my target t
            }
            #pragma unroll
            for (int j = 0; j < 16; j++) {
                h = fmaf(da[j], h, db[j]);
                pr[j] = h * cc[j];
            }
            // transpose-reduce: 16 values over 16 lanes in 15 shuffles; lane s -> sum for t=tb*16+s
            float w8[8];
            #pragma unroll
            for (int k = 0; k < 8; k++) {
                float a = pr[2 * k], bv = pr[2 * k + 1];
                float keep = (s & 1) ? bv : a;
                float send = (s & 1) ? a : bv;
                w8[k] = keep + __shfl_xor(send, 1);
            }
            float u4[4];
            #pragma unroll
            for (int k = 0; k < 4; k++) {
                float a = w8[2 * k], bv = w8[2 * k + 1];
                float keep = (s & 2) ? bv : a;
                float send = (s & 2) ? a : bv;
                u4[k] = keep + __shfl_xor(send, 2);
            }
            float x2[2];
            #pragma unroll
            for (int k = 0; k < 2; k++) {
                float a = u4[2 * k], bv = u4[2 * k + 1];
                float keep = (s & 4) ? bv : a;
                float send = (s & 4) ? a : bv;
                x2[k] = keep + __shfl_xor(send, 4);
            }
            float a0 = x2[0], b0 = x2[1];
            float keep = (s & 8) ? b0 : a0;
            float send = (s & 8) ? a0 : b0;
            float res = keep + __shfl_xor(send, 8);
            // epilogue on own lane: t = tb*16 + s
            int t = (tb << 4) + s;
            float zv = s_z[bf][t][dl];
            float y = res + myud;
            s_y[yb][t * 17 + dl] = y * (zv / (1.f + __expf(-zv)));
        }
        __syncthreads();
        // bulk store y chunk -> bf16 (gather from padded LDS)
        {
            int t0_ = c * T_CH;
            int tt = tid >> 2, qq = (tid & 3) << 2;
            us4 o;
            o.x = f2b(s_y[yb][tt * 17 + qq + 0]);
            o.y = f2b(s_y[yb][tt * 17 + qq + 1]);
            o.z = f2b(s_y[yb][tt * 17 + qq + 2]);
            o.w = f2b(s_y[yb][tt * 17 + qq + 3]);
            *(us4*)(Yb + (size_t)(t0_ + tt) * 512 + qq) = o;
        }
        bf ^= 1;
    }
    #undef STAGE
}

extern "C" void kernel_launch(void* const* d_in, const int* in_sizes, int n_in,
                              void* d_out, int out_size, void* d_ws, size_t ws_size,
                              hipStream_t stream) {
    (void)in_sizes; (void)n_in; (void)out_size; (void)ws_size;
    const float* x         = (const float*)d_in[0];
    const float* ln_g      = (const float*)d_in[1];
    const float* ln_b      = (const float*)d_in[2];
    const float* in_proj_w = (const float*)d_in[3];
    const float* conv_w    = (const float*)d_in[4];
    const float* conv_b    = (const float*)d_in[5];
    const float* x_proj_w  = (const float*)d_in[6];
    const float* dt_proj_w = (const float*)d_in[7];
    const float* dt_proj_b = (const float*)d_in[8];
    const float* A_log     = (const float*)d_in[9];
    const float* Dp        = (const float*)d_in[10];
    const float* out_proj_w= (const float*)d_in[11];
    const float* mlp_ln_g  = (const float*)d_in[12];
    const float* mlp_ln_b  = (const float*)d_in[13];
    const float* mlp_w1    = (const float*)d_in[14];
    const float* mlp_b1    = (const float*)d_in[15];
    const float* mlp_w2    = (const float*)d_in[16];
    const float* mlp_b2    = (const float*)d_in[17];

    float* ws  = (float*)d_ws;
    u16*   XNB = (u16*)(ws + OFF_XNB);
    u16*   XCB = (u16*)(ws + OFF_XNB);     // conv out bf16 (XNB dead after in_proj)
    float* XZ  = ws + OFF_XZ;
    u16*   H   = (u16*)(ws + OFF_XZ);      // mlp hidden bf16, aliases XZ
    float* XC  = ws + OFF_XC;
    float* DBL = ws + OFF_DBL;
    float* DT  = ws + OFF_DT;
    float* XF2 = ws + OFF_XF2;
    u16*   YB  = (u16*)(ws + OFF_YB);
    u16*   WB  = (u16*)(ws + OFF_WB);
    float* out = (float*)d_out;

    // 0. weights -> bf16
    cvt5_kernel<<<3680, 256, 0, stream>>>(in_proj_w, out_proj_w, mlp_w1, mlp_w2, x_proj_w, WB);
    // 1. LN1 on transposed x -> XNB (bf16)
    ln_kernel<<<N_TOK, 256, 0, stream>>>(x, ln_g, ln_b, XNB, 1);
    // 2. in_proj: XZ = XNB @ in_proj_w^T  (fp32 out)
    gemm_mfma<0><<<dim3(8, 64), 256, 0, stream>>>(XNB, WB + WB_IN, XZ, N_TOK, 1024, 256, nullptr, nullptr);
    // 3. depthwise conv + silu -> XC (fp32) + XCB (bf16)
    conv_kernel<<<(N_TOK * D_INNER) / 256, 256, 0, stream>>>(XZ, conv_w, conv_b, XC, XCB);
    // 4a. x_proj (MFMA, 256 blocks) -> DBL (all 48 cols)
    xproj3_kernel<<<256, 128, 0, stream>>>(XCB, WB + WB_XP, DBL);
    // 4b. dt_proj + softplus (wide memory-bound) -> DT
    dtproj_kernel<<<4096, 256, 0, stream>>>(DBL, dt_proj_w, dt_proj_b, DT);
    // 5. selective scan + *silu(z) -> YB (bf16)
    scan_kernel<<<256, 256, 0, stream>>>(XC, DBL, DT, XZ, A_log, Dp, YB);
    // 6. out_proj + residual(x transposed) -> XF2 (fp32)
    gemm_mfma<1><<<dim3(2, 64), 256, 0, stream>>>(YB, WB + WB_OUT, XF2, N_TOK, 256, 512, nullptr, x);
    // 7. LN2 -> XNB (bf16, reuse)
    ln_kernel<<<N_TOK, 256, 0, stream>>>(XF2, mlp_ln_g, mlp_ln_b, XNB, 0);
    // 8. MLP fc1 + bias + gelu -> H (bf16, aliases XZ)
    gemm_mfma<2><<<dim3(8, 64), 256, 0, stream>>>(XNB, WB + WB_W1, H, N_TOK, 1024, 256, mlp_b1, nullptr);
    // 9. MLP fc2 + b2 + residual(XF2), transposed fp32 store -> d_out
    gemm_mfma<3><<<dim3(2, 64), 256, 0, stream>>>(H, WB + WB_W2, out, N_TOK, 256, 1024, mlp_b2, XF2);
}

// Round 8
// 324.251 us; speedup vs baseline: 3.8304x; 1.0238x over previous
//
#include <hip/hip_runtime.h>
#include <math.h>

#define DIM      256
#define L_SEQ    1024
#define B_SZ     8
#define D_INNER  512
#define D_STATE  16
#define DT_RANK  16
#define N_TOK    (B_SZ * L_SEQ)   // 8192
#define T_CH     64

typedef unsigned short u16;
typedef __attribute__((ext_vector_type(4))) float f32x4;
typedef __attribute__((ext_vector_type(8))) short short8;
struct __align__(8) us4 { u16 x, y, z, w; };

// ---- workspace float offsets (87.3 MB, NO overlapping live buffers) ----
#define OFF_WB   0                     // bf16 weights                  (  471,040)
#define OFF_XT   471040                // fp32 8192x256 token-major x   (2,097,152)
#define OFF_XNB  2568192               // bf16 8192x256 LN out          (1,048,576)
#define OFF_XZ   3616768               // fp32 8192x1024 xz             (8,388,608)
#define OFF_XC   12005376              // fp32 8192x512 u               (4,194,304)
#define OFF_DBL  16199680              // fp32 8192x48                  (  393,216)
#define OFF_DT   16592896              // fp32 8192x512 dt              (4,194,304)
#define OFF_YB   20787200              // bf16 8192x512 y               (1,048,576)
// aliases onto dead regions:
//   XF2 (fp32 2M)  -> XC[0..2M)    (XC=u dead after scan)
//   TOUT (fp32 2M) -> XC[2M..4M)
//   H (bf16, 2M fl)-> XZ[0..2M)    (XZ dead after scan)
#define OFF_XF2  OFF_XC
#define OFF_TOUT (OFF_XC + 2097152)
#define OFF_H    OFF_XZ
// WB sub-offsets in u16 elements
#define WB_IN    0
#define WB_OUT   262144
#define WB_W1    393216
#define WB_W2    655360
#define WB_XP    917504

__device__ __forceinline__ u16 f2b(float f) {
    unsigned int u = __float_as_uint(f);
    return (u16)((u + 0x7fffu + ((u >> 16) & 1u)) >> 16);   // RNE
}

// ---------------- weight fp32->bf16 convert (5 segments) ----------------
__global__ __launch_bounds__(256) void cvt5_kernel(const float* __restrict__ a,
                                                   const float* __restrict__ b,
                                                   const float* __restrict__ c,
                                                   const float* __restrict__ d,
                                                   const float* __restrict__ e,
                                                   u16* __restrict__ out) {
    int i = blockIdx.x * 256 + threadIdx.x;   // total 942080
    const float* src; int off;
    if (i < 262144)      { src = a; off = i; }
    else if (i < 393216) { src = b; off = i - 262144; }
    else if (i < 655360) { src = c; off = i - 393216; }
    else if (i < 917504) { src = d; off = i - 655360; }
    else                 { src = e; off = i - 917504; }
    out[i] = f2b(src[off]);
}

// ---------------- transpose in: x (8,256,1024) -> XT (8192,256) ----------------
__global__ __launch_bounds__(256) void tin_kernel(const float* __restrict__ x,
                                                  float* __restrict__ XT) {
    __shared__ float tile[64][65];
    int bb = blockIdx.x >> 6, c0 = ((blockIdx.x >> 4) & 3) << 6, l0 = (blockIdx.x & 15) << 6;
    int tr = threadIdx.x >> 6, tc = threadIdx.x & 63;
    const float* src = x + ((size_t)bb * 256 + c0) * 1024 + l0;
    #pragma unroll
    for (int i = 0; i < 16; i++) tile[tr + i * 4][tc] = src[(size_t)(tr + i * 4) * 1024 + tc];
    __syncthreads();
    float* dst = XT + ((size_t)bb * 1024 + l0) * 256 + c0;
    #pragma unroll
    for (int i = 0; i < 16; i++) dst[(size_t)(tr + i * 4) * 256 + tc] = tile[tc][tr + i * 4];
}

// ---------------- transpose out: TOUT (8192,256) -> out (8,256,1024) ----------------
__global__ __launch_bounds__(256) void tout_kernel(const float* __restrict__ T,
                                                   float* __restrict__ outp) {
    __shared__ float tile[64][65];
    int bb = blockIdx.x >> 6, c0 = ((blockIdx.x >> 4) & 3) << 6, l0 = (blockIdx.x & 15) << 6;
    int tr = threadIdx.x >> 6, tc = threadIdx.x & 63;
    const float* src = T + ((size_t)bb * 1024 + l0) * 256 + c0;
    #pragma unroll
    for (int i = 0; i < 16; i++) tile[tr + i * 4][tc] = src[(size_t)(tr + i * 4) * 256 + tc];
    __syncthreads();
    float* dst = outp + ((size_t)bb * 256 + c0) * 1024 + l0;
    #pragma unroll
    for (int i = 0; i < 16; i++) dst[(size_t)(tr + i * 4) * 1024 + tc] = tile[tc][tr + i * 4];
}

// ---------------- LayerNorm over C=256, one block per token; bf16 out ----------------
__global__ __launch_bounds__(256) void ln_kernel(const float* __restrict__ in,
                                                 const float* __restrict__ g,
                                                 const float* __restrict__ b,
                                                 u16* __restrict__ out) {
    int token = blockIdx.x;
    int c = threadIdx.x;
    float v = in[(size_t)token * DIM + c];
    float s = v, s2 = v * v;
    #pragma unroll
    for (int o = 32; o; o >>= 1) {
        s  += __shfl_down(s, o);
        s2 += __shfl_down(s2, o);
    }
    __shared__ float red[8];
    int w = threadIdx.x >> 6;
    if ((threadIdx.x & 63) == 0) { red[w] = s; red[4 + w] = s2; }
    __syncthreads();
    if (threadIdx.x == 0) {
        float a = 0.f, aa = 0.f;
        for (int i = 0; i < 4; i++) { a += red[i]; aa += red[4 + i]; }
        red[0] = a; red[4] = aa;
    }
    __syncthreads();
    float mean = red[0] * (1.f / DIM);
    float var  = red[4] * (1.f / DIM) - mean * mean;
    float rstd = rsqrtf(var + 1e-5f);
    out[(size_t)token * DIM + c] = f2b((v - mean) * rstd * g[c] + b[c]);
}

// ---------------- global->LDS async helper (16B) ----------------
__device__ __forceinline__ void gload16(const void* g, void* l) {
    __builtin_amdgcn_global_load_lds(
        (const __attribute__((address_space(1))) unsigned int*)g,
        (__attribute__((address_space(3))) unsigned int*)l,
        16, 0, 0);
}

// ---------------- bf16 MFMA GEMM: C[M,N] = A[M,K] @ W[N,K]^T ----------------
// EPI: 0 plain fp32; 1 fp32 + extra[m*DIM+n]; 2 bias+gelu bf16; 3 bias + extra[m*DIM+n] fp32
template <int EPI>
__global__ __launch_bounds__(256) void gemm_mfma(const u16* __restrict__ A,
                                                 const u16* __restrict__ W,
                                                 void* __restrict__ Cout,
                                                 int M, int N, int K,
                                                 const float* __restrict__ bias,
                                                 const float* __restrict__ extra) {
    __shared__ u16 Als[4096];   // [128][32] bf16
    __shared__ u16 Bls[4096];
    int tid = threadIdx.x;
    int w = tid >> 6, l = tid & 63;
    int m0 = blockIdx.y << 7, n0 = blockIdx.x << 7;

    int srow = tid >> 2;
    int scol = (tid & 3) << 3;
    const u16* Ag  = A + (size_t)(m0 + srow) * K + scol;
    const u16* Ag2 = A + (size_t)(m0 + 64 + srow) * K + scol;
    const u16* Wg  = W + (size_t)(n0 + srow) * K + scol;
    const u16* Wg2 = W + (size_t)(n0 + 64 + srow) * K + scol;
    u16* Ab0 = Als + (w << 9);
    u16* Ab1 = Als + 2048 + (w << 9);
    u16* Bb0 = Bls + (w << 9);
    u16* Bb1 = Bls + 2048 + (w << 9);

    int wr = (w >> 1) << 6, wc = (w & 1) << 6;
    int fr = l & 15, fk = (l >> 4) << 3;

    f32x4 acc[4][4] = {};
    for (int k0 = 0; k0 < K; k0 += 32) {
        gload16(Ag + k0, Ab0);
        gload16(Ag2 + k0, Ab1);
        gload16(Wg + k0, Bb0);
        gload16(Wg2 + k0, Bb1);
        __syncthreads();
        short8 af[4], bfr[4];
        #pragma unroll
        for (int i = 0; i < 4; i++)
            af[i] = *(const short8*)&Als[(wr + i * 16 + fr) * 32 + fk];
        #pragma unroll
        for (int j = 0; j < 4; j++)
            bfr[j] = *(const short8*)&Bls[(wc + j * 16 + fr) * 32 + fk];
        #pragma unroll
        for (int i = 0; i < 4; i++)
            #pragma unroll
            for (int j = 0; j < 4; j++)
                acc[i][j] = __builtin_amdgcn_mfma_f32_16x16x32_bf16(af[i], bfr[j], acc[i][j], 0, 0, 0);
        __syncthreads();
    }

    int cr = (l >> 4) << 2;
    int ccol = l & 15;
    #pragma unroll
    for (int i = 0; i < 4; i++) {
        #pragma unroll
        for (int j = 0; j < 4; j++) {
            int n = n0 + wc + j * 16 + ccol;
            #pragma unroll
            for (int r = 0; r < 4; r++) {
                int m = m0 + wr + i * 16 + cr + r;
                float v = acc[i][j][r];
                if (EPI == 0) {
                    ((float*)Cout)[(size_t)m * N + n] = v;
                } else if (EPI == 1) {
                    ((float*)Cout)[(size_t)m * N + n] = v + extra[(size_t)m * DIM + n];
                } else if (EPI == 2) {
                    v += bias[n];
                    ((u16*)Cout)[(size_t)m * N + n] = f2b(0.5f * v * (1.f + erff(v * 0.70710678118f)));
                } else {
                    v += bias[n] + extra[(size_t)m * DIM + n];
                    ((float*)Cout)[(size_t)m * N + n] = v;
                }
            }
        }
    }
}

// ---------------- depthwise causal conv (k=4) + silu; fp32 out only ----------------
__global__ __launch_bounds__(256) void conv_kernel(const float* __restrict__ XZ,
                                                   const float* __restrict__ cw,
                                                   const float* __restrict__ cb,
                                                   float* __restrict__ XC) {
    int idx = blockIdx.x * 256 + threadIdx.x;
    int d = idx & 511;
    int token = idx >> 9;
    int l = token & 1023, b = token >> 10;
    const float* base = XZ + (size_t)b * L_SEQ * 1024 + d;
    float acc = cb[d];
    #pragma unroll
    for (int j = 0; j < 4; j++) {
        int ls = l - 3 + j;
        if (ls >= 0) acc = fmaf(base[(size_t)ls * 1024], cw[d * 4 + j], acc);
    }
    XC[(size_t)token * 512 + d] = acc / (1.f + __expf(-acc));
}

// ---------------- xproj v3b: MFMA x_proj from fp32 XC (in-register cvt) ----------------
// 256 blocks x 128 threads (2 waves); wave w: rows w*16..+15, 3 col-frags (48 cols).
__global__ __launch_bounds__(128) void xproj3_kernel(const float* __restrict__ XCf,
                                                     const u16* __restrict__ WXP,
                                                     float* __restrict__ DBL) {
    __shared__ float dbl_s[32][49];
    int tid = threadIdx.x;
    int w = tid >> 6, l = tid & 63;
    int m0 = blockIdx.x << 5;
    int fr = l & 15, fk = (l >> 4) << 3;
    const float* Af = XCf + (size_t)(m0 + (w << 4) + fr) * 512 + fk;
    const u16* Wb = WXP + (size_t)fr * 512 + fk;
    f32x4 acc[3] = {};
    for (int k0 = 0; k0 < 512; k0 += 32) {
        float4 fa = *(const float4*)(Af + k0);
        float4 fb = *(const float4*)(Af + k0 + 4);
        short8 a0;
        a0[0] = (short)f2b(fa.x); a0[1] = (short)f2b(fa.y);
        a0[2] = (short)f2b(fa.z); a0[3] = (short)f2b(fa.w);
        a0[4] = (short)f2b(fb.x); a0[5] = (short)f2b(fb.y);
        a0[6] = (short)f2b(fb.z); a0[7] = (short)f2b(fb.w);
        short8 b0 = *(const short8*)(Wb + k0);
        short8 b1 = *(const short8*)(Wb + 16 * 512 + k0);
        short8 b2 = *(const short8*)(Wb + 32 * 512 + k0);
        acc[0] = __builtin_amdgcn_mfma_f32_16x16x32_bf16(a0, b0, acc[0], 0, 0, 0);
        acc[1] = __builtin_amdgcn_mfma_f32_16x16x32_bf16(a0, b1, acc[1], 0, 0, 0);
        acc[2] = __builtin_amdgcn_mfma_f32_16x16x32_bf16(a0, b2, acc[2], 0, 0, 0);
    }
    int cr = (l >> 4) << 2, ccol = l & 15;
    #pragma unroll
    for (int j = 0; j < 3; j++)
        #pragma unroll
        for (int r = 0; r < 4; r++)
            dbl_s[(w << 4) + cr + r][j * 16 + ccol] = acc[j][r];
    __syncthreads();
    #pragma unroll
    for (int it = 0; it < 3; it++) {
        int fidx = it * 512 + tid * 4;
        int row = fidx / 48, col = fidx % 48;
        float4 v;
        v.x = dbl_s[row][col]; v.y = dbl_s[row][col + 1];
        v.z = dbl_s[row][col + 2]; v.w = dbl_s[row][col + 3];
        *(float4*)(DBL + (size_t)(m0 + row) * 48 + col) = v;
    }
}

// ---------------- dt_proj + softplus ----------------
__global__ __launch_bounds__(256) void dtproj_kernel(const float* __restrict__ DBL,
                                                     const float* __restrict__ wdt,
                                                     const float* __restrict__ wdb,
                                                     float* __restrict__ DT) {
    int idx = blockIdx.x * 256 + threadIdx.x;
    int token = idx >> 7, q = idx & 127;
    int d0 = q << 2;
    const float4* dtr4 = (const float4*)(DBL + (size_t)token * 48);
    float4 t0 = dtr4[0], t1 = dtr4[1], t2 = dtr4[2], t3 = dtr4[3];
    float4 ov;
    #pragma unroll
    for (int qq = 0; qq < 4; qq++) {
        int d = d0 + qq;
        const float4* wr = (const float4*)(wdt + (size_t)d * 16);
        float4 w0 = wr[0], w1 = wr[1], w2 = wr[2], w3 = wr[3];
        float a = wdb[d];
        a += t0.x * w0.x + t0.y * w0.y + t0.z * w0.z + t0.w * w0.w;
        a += t1.x * w1.x + t1.y * w1.y + t1.z * w1.z + t1.w * w1.w;
        a += t2.x * w2.x + t2.y * w2.y + t2.z * w2.z + t2.w * w2.w;
        a += t3.x * w3.x + t3.y * w3.y + t3.z * w3.z + t3.w * w3.w;
        ((float*)&ov)[qq] = (a > 20.f) ? a : log1pf(__expf(a));
    }
    *(float4*)(DT + (size_t)token * 512 + d0) = ov;
}

// ---------------- selective scan v4 (round-6 proven): transpose-reduce ----------------
__global__ __launch_bounds__(256) void scan_kernel(const float* __restrict__ U,
                                                   const float* __restrict__ DBL,
                                                   const float* __restrict__ DT,
                                                   const float* __restrict__ XZ,
                                                   const float* __restrict__ A_log,
                                                   const float* __restrict__ Dp,
                                                   u16* __restrict__ YB) {
    __shared__ float s_dt[2][T_CH][16];
    __shared__ float s_u [2][T_CH][16];
    __shared__ float s_BC[2][T_CH][32];
    __shared__ float s_z [2][T_CH][16];
    __shared__ float s_y [2][T_CH * 17];   // padded stride 17

    int blk = blockIdx.x;
    int b = blk >> 5, ch = blk & 31;
    int tid = threadIdx.x;
    int s = tid & 15, dl = tid >> 4;
    int d = ch * 16 + dl;
    int w = tid >> 6;

    float Ads = -__expf(A_log[d * D_STATE + s]);
    float Dv = Dp[d];

    const float* DTb = DT  + (size_t)b * L_SEQ * D_INNER + ch * 16;
    const float* Ub  = U   + (size_t)b * L_SEQ * D_INNER + ch * 16;
    const float* DBb = DBL + (size_t)b * L_SEQ * 48 + 16;
    const float* Zb  = XZ  + (size_t)b * L_SEQ * 1024 + 512 + ch * 16;
    u16* Yb          = YB  + (size_t)b * L_SEQ * D_INNER + ch * 16;

    int r16 = tid >> 2, q16 = (tid & 3) << 2;
    int r32 = tid >> 3, q32 = (tid & 7) << 2;

    #define STAGE(c, bf) { \
        int t0_ = (c) * T_CH; \
        gload16(DTb + (size_t)(t0_ + r16) * 512 + q16, &s_dt[bf][0][0] + (w << 8)); \
        gload16(Ub  + (size_t)(t0_ + r16) * 512 + q16, &s_u [bf][0][0] + (w << 8)); \
        gload16(Zb  + (size_t)(t0_ + r16) * 1024 + q16, &s_z[bf][0][0] + (w << 8)); \
        gload16(DBb + (size_t)(t0_ + r32) * 48 + q32, &s_BC[bf][0][0] + (w << 8)); \
        gload16(DBb + (size_t)(t0_ + 32 + r32) * 48 + q32, &s_BC[bf][0][0] + 1024 + (w << 8)); \
    }

    float h = 0.f;
    int bf = 0;
    STAGE(0, 0);
    __syncthreads();

    for (int c = 0; c < L_SEQ / T_CH; c++) {
        if (c + 1 < L_SEQ / T_CH) STAGE(c + 1, bf ^ 1);
        int yb = c & 1;
        #pragma unroll 1
        for (int tb = 0; tb < 4; tb++) {
            float da[16], db[16], cc[16], pr[16];
            float myud = 0.f;
            #pragma unroll
            for (int j = 0; j < 16; j++) {
                int t = (tb << 4) + j;
                float dtv = s_dt[bf][t][dl];
                float uv  = s_u [bf][t][dl];
                float bs  = s_BC[bf][t][s];
                float cs  = s_BC[bf][t][16 + s];
                da[j] = __expf(dtv * Ads);
                db[j] = dtv * bs * uv;
                cc[j] = cs;
                myud = (s == j) ? uv * Dv : myud;
            }
            #pragma unroll
            for (int j = 0; j < 16; j++) {
                h = fmaf(da[j], h, db[j]);
                pr[j] = h * cc[j];
            }
            // transpose-reduce: lane s ends with the sum for t = tb*16+s
            float w8[8];
            #pragma unroll
            for (int k = 0; k < 8; k++) {
                float a = pr[2 * k], bv = pr[2 * k + 1];
                float keep = (s & 1) ? bv : a;
                float send = (s & 1) ? a : bv;
                w8[k] = keep + __shfl_xor(send, 1);
            }
            float u4[4];
            #pragma unroll
            for (int k = 0; k < 4; k++) {
                float a = w8[2 * k], bv = w8[2 * k + 1];
                float keep = (s & 2) ? bv : a;
                float send = (s & 2) ? a : bv;
                u4[k] = keep + __shfl_xor(send, 2);
            }
            float x2[2];
            #pragma unroll
            for (int k = 0; k < 2; k++) {
                float a = u4[2 * k], bv = u4[2 * k + 1];
                float keep = (s & 4) ? bv : a;
                float send = (s & 4) ? a : bv;
                x2[k] = keep + __shfl_xor(send, 4);
            }
            float a0 = x2[0], b0 = x2[1];
            float keep = (s & 8) ? b0 : a0;
            float send = (s & 8) ? a0 : b0;
            float res = keep + __shfl_xor(send, 8);
            int t = (tb << 4) + s;
            float zv = s_z[bf][t][dl];
            float y = res + myud;
            s_y[yb][t * 17 + dl] = y * (zv / (1.f + __expf(-zv)));
        }
        __syncthreads();
        {
            int t0_ = c * T_CH;
            int tt = tid >> 2, qq = (tid & 3) << 2;
            us4 o;
            o.x = f2b(s_y[yb][tt * 17 + qq + 0]);
            o.y = f2b(s_y[yb][tt * 17 + qq + 1]);
            o.z = f2b(s_y[yb][tt * 17 + qq + 2]);
            o.w = f2b(s_y[yb][tt * 17 + qq + 3]);
            *(us4*)(Yb + (size_t)(t0_ + tt) * 512 + qq) = o;
        }
        bf ^= 1;
    }
    #undef STAGE
}

extern "C" void kernel_launch(void* const* d_in, const int* in_sizes, int n_in,
                              void* d_out, int out_size, void* d_ws, size_t ws_size,
                              hipStream_t stream) {
    (void)in_sizes; (void)n_in; (void)out_size; (void)ws_size;
    const float* x         = (const float*)d_in[0];
    const float* ln_g      = (const float*)d_in[1];
    const float* ln_b      = (const float*)d_in[2];
    const float* in_proj_w = (const float*)d_in[3];
    const float* conv_w    = (const float*)d_in[4];
    const float* conv_b    = (const float*)d_in[5];
    const float* x_proj_w  = (const float*)d_in[6];
    const float* dt_proj_w = (const float*)d_in[7];
    const float* dt_proj_b = (const float*)d_in[8];
    const float* A_log     = (const float*)d_in[9];
    const float* Dp        = (const float*)d_in[10];
    const float* out_proj_w= (const float*)d_in[11];
    const float* mlp_ln_g  = (const float*)d_in[12];
    const float* mlp_ln_b  = (const float*)d_in[13];
    const float* mlp_w1    = (const float*)d_in[14];
    const float* mlp_b1    = (const float*)d_in[15];
    const float* mlp_w2    = (const float*)d_in[16];
    const float* mlp_b2    = (const float*)d_in[17];

    float* ws  = (float*)d_ws;
    u16*   WB  = (u16*)(ws + OFF_WB);
    float* XT  = ws + OFF_XT;
    u16*   XNB = (u16*)(ws + OFF_XNB);
    float* XZ  = ws + OFF_XZ;
    float* XC  = ws + OFF_XC;
    float* DBL = ws + OFF_DBL;
    float* DT  = ws + OFF_DT;
    u16*   YB  = (u16*)(ws + OFF_YB);
    float* XF2 = ws + OFF_XF2;             // alias XC[0..2M)   (dead after scan)
    float* TOUT= ws + OFF_TOUT;            // alias XC[2M..4M)
    u16*   H   = (u16*)(ws + OFF_H);       // alias XZ[0..2M)   (dead after scan)
    float* out = (float*)d_out;

    // 0. weights -> bf16
    cvt5_kernel<<<3680, 256, 0, stream>>>(in_proj_w, out_proj_w, mlp_w1, mlp_w2, x_proj_w, WB);
    // 1. transpose x -> XT (token-major)
    tin_kernel<<<512, 256, 0, stream>>>(x, XT);
    // 2. LN1 -> XNB (bf16)
    ln_kernel<<<N_TOK, 256, 0, stream>>>(XT, ln_g, ln_b, XNB);
    // 3. in_proj: XZ = XNB @ W^T
    gemm_mfma<0><<<dim3(8, 64), 256, 0, stream>>>(XNB, WB + WB_IN, XZ, N_TOK, 1024, 256, nullptr, nullptr);
    // 4. conv + silu -> XC (fp32)
    conv_kernel<<<(N_TOK * D_INNER) / 256, 256, 0, stream>>>(XZ, conv_w, conv_b, XC);
    // 5. x_proj (fp32 A, in-reg cvt) -> DBL
    xproj3_kernel<<<256, 128, 0, stream>>>(XC, WB + WB_XP, DBL);
    // 6. dt_proj + softplus -> DT
    dtproj_kernel<<<4096, 256, 0, stream>>>(DBL, dt_proj_w, dt_proj_b, DT);
    // 7. selective scan + *silu(z) -> YB (bf16)
    scan_kernel<<<256, 256, 0, stream>>>(XC, DBL, DT, XZ, A_log, Dp, YB);
    // 8. out_proj + residual(XT) -> XF2
    gemm_mfma<1><<<dim3(2, 64), 256, 0, stream>>>(YB, WB + WB_OUT, XF2, N_TOK, 256, 512, nullptr, XT);
    // 9. LN2 -> XNB
    ln_kernel<<<N_TOK, 256, 0, stream>>>(XF2, mlp_ln_g, mlp_ln_b, XNB);
    // 10. fc1 + bias + gelu -> H (bf16)
    gemm_mfma<2><<<dim3(8, 64), 256, 0, stream>>>(XNB, WB + WB_W1, H, N_TOK, 1024, 256, mlp_b1, nullptr);
    // 11. fc2 + b2 + residual(XF2) -> TOUT (token-major)
    gemm_mfma<3><<<dim3(2, 64), 256, 0, stream>>>(H, WB + WB_W2, TOUT, N_TOK, 256, 1024, mlp_b2, XF2);
    // 12. transpose TOUT -> d_out
    tout_kernel<<<512, 256, 0, stream>>>(TOUT, out);
}